// Round 1
// baseline (627.347 us; speedup 1.0000x reference)
//
#include <hip/hip_runtime.h>

// MSARowAttentionWithPairBias — round 1 baseline.
// fp32 compute (no fp32 MFMA on CDNA4 -> vector ALU), bf16 only inside
// attention LDS tiles (fp32 accumulate). Error budget ~1e-4 vs 3.59e-4 thresh.
//
// Shapes: B=1 S=128 I=256 CS=256 CZ=128 H=8 D=32 TOT=256, ROWS=S*I=32768.
// ws layout (floats): m[32768*256] | Q | K | V | G | bias[8*65536]
//   gv aliases m (m dead after QKVG GEMMs). Total ~170 MB.

typedef unsigned short bfraw;
typedef bfraw bfx8 __attribute__((ext_vector_type(8)));
typedef bfraw bfx4 __attribute__((ext_vector_type(4)));

__device__ __forceinline__ float bf2f(bfraw u) {
  return __uint_as_float(((unsigned)u) << 16);
}
__device__ __forceinline__ bfraw f2bf(float f) {
  unsigned x = __float_as_uint(f);
  unsigned r = x + 0x7fffu + ((x >> 16) & 1u);   // RNE
  return (bfraw)(r >> 16);
}

// ---------------- LayerNorm over msa rows (256 wide), wave per row ----------
__global__ __launch_bounds__(256) void ln_msa_k(const float* __restrict__ x,
    const float* __restrict__ g, const float* __restrict__ b,
    float* __restrict__ out)
{
  int row  = blockIdx.x * 4 + (threadIdx.x >> 6);
  int lane = threadIdx.x & 63;
  int base = row * 256 + lane * 4;
  float4 v = *(const float4*)(x + base);
  float s  = (v.x + v.y) + (v.z + v.w);
  float ss = (v.x*v.x + v.y*v.y) + (v.z*v.z + v.w*v.w);
  #pragma unroll
  for (int mk = 32; mk >= 1; mk >>= 1) {
    s  += __shfl_xor(s, mk);
    ss += __shfl_xor(ss, mk);
  }
  float mu  = s * (1.0f/256.0f);
  float var = ss * (1.0f/256.0f) - mu*mu;     // population var (jnp.var)
  float rs  = rsqrtf(var + 1e-5f);
  float4 gg = *(const float4*)(g + lane*4);
  float4 bb = *(const float4*)(b + lane*4);
  float4 o;
  o.x = (v.x - mu) * rs * gg.x + bb.x;
  o.y = (v.y - mu) * rs * gg.y + bb.y;
  o.z = (v.z - mu) * rs * gg.z + bb.z;
  o.w = (v.w - mu) * rs * gg.w + bb.w;
  *(float4*)(out + base) = o;
}

// ------------- pair LayerNorm (128 wide) + @Wp -> bias[h][i][j] -------------
__global__ __launch_bounds__(256) void ln_pair_bias_k(const float* __restrict__ pair,
    const float* __restrict__ g, const float* __restrict__ b,
    const float* __restrict__ Wp, float* __restrict__ bias)
{
  int row  = blockIdx.x * 4 + (threadIdx.x >> 6);   // i*256 + j
  int lane = threadIdx.x & 63;
  int base = row * 128 + lane * 2;
  float2 v = *(const float2*)(pair + base);
  float s  = v.x + v.y;
  float ss = v.x*v.x + v.y*v.y;
  #pragma unroll
  for (int mk = 32; mk >= 1; mk >>= 1) {
    s  += __shfl_xor(s, mk);
    ss += __shfl_xor(ss, mk);
  }
  float mu  = s * (1.0f/128.0f);
  float var = ss * (1.0f/128.0f) - mu*mu;
  float rs  = rsqrtf(var + 1e-5f);
  float2 gg = *(const float2*)(g + lane*2);
  float2 bb = *(const float2*)(b + lane*2);
  float p0 = (v.x - mu) * rs * gg.x + bb.x;
  float p1 = (v.y - mu) * rs * gg.y + bb.y;
  const float* w0 = Wp + (lane*2) * 8;   // Wp[c][h], row-major
  float acc[8];
  #pragma unroll
  for (int hh = 0; hh < 8; ++hh)
    acc[hh] = p0 * w0[hh] + p1 * w0[8 + hh];
  #pragma unroll
  for (int mk = 32; mk >= 1; mk >>= 1)
    #pragma unroll
    for (int hh = 0; hh < 8; ++hh)
      acc[hh] += __shfl_xor(acc[hh], mk);
  #pragma unroll
  for (int hh = 0; hh < 8; ++hh)
    if (lane == hh)
      bias[hh * 65536 + row] = acc[hh];
}

// -------- fp32 GEMM: C[32768x256] = A[32768x256] @ W[256x256] (+bias,sig) ---
// BM=BN=128 BK=32, 256 thr, 8x8 micro-tile. A transposed in LDS -> b128 frags.
__global__ __launch_bounds__(256) void gemm128_k(const float* __restrict__ A,
    const float* __restrict__ W, const float* __restrict__ bias,
    float* __restrict__ C, int do_sig)
{
  __shared__ float As[32][132];   // [k][m], +4 pad
  __shared__ float Bs[32][132];   // [k][n]
  const int t = threadIdx.x;
  const int ty = t >> 4, tx = t & 15;
  const int bm = blockIdx.x * 128, bn = blockIdx.y * 128;
  float acc[8][8];
  #pragma unroll
  for (int i = 0; i < 8; ++i)
    #pragma unroll
    for (int j = 0; j < 8; ++j) acc[i][j] = 0.f;

  for (int k0 = 0; k0 < 256; k0 += 32) {
    #pragma unroll
    for (int r = 0; r < 4; ++r) {
      int idx = r * 256 + t;
      int row = idx >> 3, kc = (idx & 7) << 2;
      float4 v = *(const float4*)(A + (bm + row) * 256 + k0 + kc);
      As[kc+0][row] = v.x; As[kc+1][row] = v.y;
      As[kc+2][row] = v.z; As[kc+3][row] = v.w;
    }
    #pragma unroll
    for (int r = 0; r < 4; ++r) {
      int idx = r * 256 + t;
      int kk = idx >> 5, nc = (idx & 31) << 2;
      *(float4*)&Bs[kk][nc] = *(const float4*)(W + (k0 + kk) * 256 + bn + nc);
    }
    __syncthreads();
    #pragma unroll 8
    for (int kk = 0; kk < 32; ++kk) {
      float a0[8], b0[8];
      *(float4*)&a0[0] = *(const float4*)&As[kk][ty*8];
      *(float4*)&a0[4] = *(const float4*)&As[kk][ty*8+4];
      *(float4*)&b0[0] = *(const float4*)&Bs[kk][tx*8];
      *(float4*)&b0[4] = *(const float4*)&Bs[kk][tx*8+4];
      #pragma unroll
      for (int i = 0; i < 8; ++i)
        #pragma unroll
        for (int j = 0; j < 8; ++j)
          acc[i][j] = fmaf(a0[i], b0[j], acc[i][j]);
    }
    __syncthreads();
  }

  #pragma unroll
  for (int i = 0; i < 8; ++i) {
    int row = bm + ty*8 + i;
    #pragma unroll
    for (int jv = 0; jv < 2; ++jv) {
      int col = bn + tx*8 + jv*4;
      float4 o;
      o.x = acc[i][jv*4+0]; o.y = acc[i][jv*4+1];
      o.z = acc[i][jv*4+2]; o.w = acc[i][jv*4+3];
      if (bias) {
        float4 bb = *(const float4*)(bias + col);
        o.x += bb.x; o.y += bb.y; o.z += bb.z; o.w += bb.w;
      }
      if (do_sig) {
        o.x = 1.0f/(1.0f + __expf(-o.x));
        o.y = 1.0f/(1.0f + __expf(-o.y));
        o.z = 1.0f/(1.0f + __expf(-o.z));
        o.w = 1.0f/(1.0f + __expf(-o.w));
      }
      *(float4*)(C + row * 256 + col) = o;
    }
  }
}

// ------------------------- fused attention per (s,h,it) ---------------------
// block = 256 thr; i-tile = 64 (blockIdx.z in 0..3). Q/K/V/P in bf16 LDS,
// fp32 accumulation. Softmax without max-subtraction (logits are O(1)):
// attn = e / l folded into the PV epilogue.
__global__ __launch_bounds__(256) void attn_k(
    const float* __restrict__ Q, const float* __restrict__ K,
    const float* __restrict__ V, const float* __restrict__ G,
    const float* __restrict__ bias, float* __restrict__ gv)
{
  __shared__ bfraw KV[256*40];   // union: Kt[32][264] (8448) / Vs[256][40] (10240)
  __shared__ bfraw Qt[32*72];    // Qt[d][il], il in 0..63
  __shared__ bfraw At[256*72];   // P[j][il], i-group XOR-swizzled

  const int s = blockIdx.x, h = blockIdx.y, it = blockIdx.z;
  const int t  = threadIdx.x;
  const int ty = t >> 5;         // i-group 0..7 (8 i each)
  const int tx = t & 31;         // scores: j-group (8 j each)

  const int qkv_base   = (s*256)*256 + h*32;          // + j*256 + d
  const int qtile_base = qkv_base + (it*64)*256;

  // stage Q tile (64 x 32) -> Qt[d][il]
  #pragma unroll
  for (int e = 0; e < 2; ++e) {
    int idx = e*256 + t;
    int il = idx >> 3, d4 = (idx & 7) << 2;
    float4 v = *(const float4*)(Q + qtile_base + il*256 + d4);
    Qt[(d4+0)*72 + il] = f2bf(v.x);
    Qt[(d4+1)*72 + il] = f2bf(v.y);
    Qt[(d4+2)*72 + il] = f2bf(v.z);
    Qt[(d4+3)*72 + il] = f2bf(v.w);
  }
  // stage K (256 x 32) -> Kt[d][j]
  #pragma unroll
  for (int e = 0; e < 8; ++e) {
    int idx = e*256 + t;
    int j = idx >> 3, d4 = (idx & 7) << 2;
    float4 v = *(const float4*)(K + qkv_base + j*256 + d4);
    KV[(d4+0)*264 + j] = f2bf(v.x);
    KV[(d4+1)*264 + j] = f2bf(v.y);
    KV[(d4+2)*264 + j] = f2bf(v.z);
    KV[(d4+3)*264 + j] = f2bf(v.w);
  }
  __syncthreads();

  // scores: acc[a][b] = Q[i]·K[j], i = it*64+ty*8+a, j = tx*8+b
  float acc[8][8];
  #pragma unroll
  for (int a = 0; a < 8; ++a)
    #pragma unroll
    for (int b = 0; b < 8; ++b) acc[a][b] = 0.f;

  #pragma unroll 4
  for (int kk = 0; kk < 32; ++kk) {
    bfx8 aq = *(const bfx8*)&Qt[kk*72 + ty*8];
    bfx8 bk = *(const bfx8*)&KV[kk*264 + tx*8];
    float qf[8], kf[8];
    #pragma unroll
    for (int u = 0; u < 8; ++u) { qf[u] = bf2f(aq[u]); kf[u] = bf2f(bk[u]); }
    #pragma unroll
    for (int a = 0; a < 8; ++a)
      #pragma unroll
      for (int b = 0; b < 8; ++b)
        acc[a][b] = fmaf(qf[a], kf[b], acc[a][b]);
  }

  // + bias, exp (no max-sub: logits O(1)), row sums l[a]
  const float scale = 0.17677669529663687f;   // 1/sqrt(32)
  const float* bp = bias + h*65536;
  float l[8];
  #pragma unroll
  for (int a = 0; a < 8; ++a) {
    int i = it*64 + ty*8 + a;
    const float* bi = bp + i*256 + tx*8;
    float4 b0 = *(const float4*)bi;
    float4 b1 = *(const float4*)(bi + 4);
    acc[a][0] = __expf(fmaf(acc[a][0], scale, b0.x));
    acc[a][1] = __expf(fmaf(acc[a][1], scale, b0.y));
    acc[a][2] = __expf(fmaf(acc[a][2], scale, b0.z));
    acc[a][3] = __expf(fmaf(acc[a][3], scale, b0.w));
    acc[a][4] = __expf(fmaf(acc[a][4], scale, b1.x));
    acc[a][5] = __expf(fmaf(acc[a][5], scale, b1.y));
    acc[a][6] = __expf(fmaf(acc[a][6], scale, b1.z));
    acc[a][7] = __expf(fmaf(acc[a][7], scale, b1.w));
    l[a] = ((acc[a][0]+acc[a][1])+(acc[a][2]+acc[a][3]))
         + ((acc[a][4]+acc[a][5])+(acc[a][6]+acc[a][7]));
  }
  #pragma unroll
  for (int mk = 1; mk <= 16; mk <<= 1)
    #pragma unroll
    for (int a = 0; a < 8; ++a)
      l[a] += __shfl_xor(l[a], mk);

  // store P (bf16) -> At[j][swizzled i-group]; swiz g' = (g + j/8 + j/32)&7
  #pragma unroll
  for (int b = 0; b < 8; ++b) {
    int j  = tx*8 + b;
    int g2 = (ty + tx + (tx >> 2)) & 7;
    bfx8 pk;
    #pragma unroll
    for (int a = 0; a < 8; ++a) pk[a] = f2bf(acc[a][b]);
    *(bfx8*)&At[j*72 + g2*8] = pk;
  }
  __syncthreads();            // Kt reads done; At complete

  // stage V -> Vs[j][d] (overwrites Kt)
  #pragma unroll
  for (int e = 0; e < 8; ++e) {
    int idx = e*256 + t;
    int j = idx >> 3, d4 = (idx & 7) << 2;
    float4 v = *(const float4*)(V + qkv_base + j*256 + d4);
    bfx4 pk;
    pk[0] = f2bf(v.x); pk[1] = f2bf(v.y); pk[2] = f2bf(v.z); pk[3] = f2bf(v.w);
    *(bfx4*)&KV[j*40 + d4] = pk;
  }
  __syncthreads();

  // PV: lanes (ty, jq = tx>>2, dg = tx&3); j = jj*8 + jq (interleaved -> no
  // stride-32 bank pathology). vacc[a][d] over this lane's 32 j's.
  const int dg = tx & 3;
  const int jq = tx >> 2;
  float vacc[8][8];
  #pragma unroll
  for (int a = 0; a < 8; ++a)
    #pragma unroll
    for (int d = 0; d < 8; ++d) vacc[a][d] = 0.f;

  #pragma unroll 4
  for (int jj = 0; jj < 32; ++jj) {
    int j  = (jj << 3) + jq;
    int g2 = (ty + jj + (jj >> 2)) & 7;     // matches write swizzle
    bfx8 ap = *(const bfx8*)&At[j*72 + g2*8];
    bfx8 vp = *(const bfx8*)&KV[j*40 + dg*8];
    float af[8], vf[8];
    #pragma unroll
    for (int u = 0; u < 8; ++u) { af[u] = bf2f(ap[u]); vf[u] = bf2f(vp[u]); }
    #pragma unroll
    for (int a = 0; a < 8; ++a)
      #pragma unroll
      for (int d = 0; d < 8; ++d)
        vacc[a][d] = fmaf(af[a], vf[d], vacc[a][d]);
  }
  #pragma unroll
  for (int mk = 4; mk <= 16; mk <<= 1)
    #pragma unroll
    for (int a = 0; a < 8; ++a)
      #pragma unroll
      for (int d = 0; d < 8; ++d)
        vacc[a][d] += __shfl_xor(vacc[a][d], mk);

  // epilogue: lane jq handles row a==jq; gv = G * vals / l
  #pragma unroll
  for (int a = 0; a < 8; ++a) {
    if (jq == a) {
      float invl = 1.0f / l[a];
      int i = it*64 + ty*8 + a;
      int obase = (s*256 + i)*256 + h*32 + dg*8;
      float4 g0 = *(const float4*)(G + obase);
      float4 g1 = *(const float4*)(G + obase + 4);
      float4 o0, o1;
      o0.x = g0.x * vacc[a][0] * invl;
      o0.y = g0.y * vacc[a][1] * invl;
      o0.z = g0.z * vacc[a][2] * invl;
      o0.w = g0.w * vacc[a][3] * invl;
      o1.x = g1.x * vacc[a][4] * invl;
      o1.y = g1.y * vacc[a][5] * invl;
      o1.z = g1.z * vacc[a][6] * invl;
      o1.w = g1.w * vacc[a][7] * invl;
      *(float4*)(gv + obase)     = o0;
      *(float4*)(gv + obase + 4) = o1;
    }
  }
}

extern "C" void kernel_launch(void* const* d_in, const int* in_sizes, int n_in,
                              void* d_out, int out_size, void* d_ws, size_t ws_size,
                              hipStream_t stream) {
  const float* msa    = (const float*)d_in[0];
  const float* pair   = (const float*)d_in[1];
  const float* ln_m_g = (const float*)d_in[2];
  const float* ln_m_b = (const float*)d_in[3];
  const float* ln_p_g = (const float*)d_in[4];
  const float* ln_p_b = (const float*)d_in[5];
  const float* Wq     = (const float*)d_in[6];
  const float* Wk     = (const float*)d_in[7];
  const float* Wv     = (const float*)d_in[8];
  const float* Wp     = (const float*)d_in[9];
  const float* Wg     = (const float*)d_in[10];
  const float* bg     = (const float*)d_in[11];
  const float* Wo     = (const float*)d_in[12];
  const float* bo     = (const float*)d_in[13];
  float* out = (float*)d_out;

  float* ws = (float*)d_ws;
  const size_t NM = 32768u * 256u;      // 8388608
  float* m     = ws;
  float* Qb    = ws + 1*NM;
  float* Kb    = ws + 2*NM;
  float* Vb    = ws + 3*NM;
  float* Gb    = ws + 4*NM;
  float* biasb = ws + 5*NM;             // 8*65536 floats
  float* gv    = m;                     // alias: m dead after QKVG GEMMs

  ln_msa_k<<<8192, 256, 0, stream>>>(msa, ln_m_g, ln_m_b, m);
  ln_pair_bias_k<<<16384, 256, 0, stream>>>(pair, ln_p_g, ln_p_b, Wp, biasb);
  gemm128_k<<<dim3(256,2), 256, 0, stream>>>(m, Wq, nullptr, Qb, 0);
  gemm128_k<<<dim3(256,2), 256, 0, stream>>>(m, Wk, nullptr, Kb, 0);
  gemm128_k<<<dim3(256,2), 256, 0, stream>>>(m, Wv, nullptr, Vb, 0);
  gemm128_k<<<dim3(256,2), 256, 0, stream>>>(m, Wg, bg, Gb, 1);
  attn_k<<<dim3(128,8,4), 256, 0, stream>>>(Qb, Kb, Vb, Gb, biasb, gv);
  gemm128_k<<<dim3(256,2), 256, 0, stream>>>(gv, Wo, bo, out, 0);
}

// Round 2
// 428.330 us; speedup vs baseline: 1.4646x; 1.4646x over previous
//
#include <hip/hip_runtime.h>

// MSARowAttentionWithPairBias — round 2: split-bf16 MFMA GEMMs.
// A' = [Ahi|Alo|Ahi] (Mx768 bf16), W'T = [Whi;Whi;Wlo] per col (Nx768 bf16);
// one fused QKVG GEMM (N=1024) + Wo GEMM via 16x16x32 bf16 MFMA,
// global_load_lds width-16 staging, 128x128 tile, 4 waves x (4x4 tiles).
// Attention unchanged (VALU) but reads bf16 Q/K/V; writes gv pre-split hi/lo.
//
// ws (bytes): Am/gv' 48M | QKV16 48M | G 32M | bias 2M | WqkvgT 1.5M | WoT .4M

typedef unsigned short bfraw;
typedef bfraw bfx8 __attribute__((ext_vector_type(8)));
typedef bfraw bfx4 __attribute__((ext_vector_type(4)));
typedef short short8 __attribute__((ext_vector_type(8)));
typedef float floatx4 __attribute__((ext_vector_type(4)));

#define NM 8388608u            // 32768*256 elements

__device__ __forceinline__ float bf2f(bfraw u) {
  return __uint_as_float(((unsigned)u) << 16);
}
__device__ __forceinline__ bfraw f2bf(float f) {
  unsigned x = __float_as_uint(f);
  unsigned r = x + 0x7fffu + ((x >> 16) & 1u);   // RNE
  return (bfraw)(r >> 16);
}

__device__ __forceinline__ void gld16(const bfraw* g, bfraw* l) {
  __builtin_amdgcn_global_load_lds(
      (const __attribute__((address_space(1))) unsigned int*)g,
      (__attribute__((address_space(3))) unsigned int*)l, 16, 0, 0);
}

// -------- LayerNorm msa rows (256 wide) -> A' = [hi|lo|hi] bf16 [row][768] --
__global__ __launch_bounds__(256) void ln_msa_k(const float* __restrict__ x,
    const float* __restrict__ g, const float* __restrict__ b,
    bfraw* __restrict__ Am)
{
  int row  = blockIdx.x * 4 + (threadIdx.x >> 6);
  int lane = threadIdx.x & 63;
  int base = row * 256 + lane * 4;
  float4 v = *(const float4*)(x + base);
  float s  = (v.x + v.y) + (v.z + v.w);
  float ss = (v.x*v.x + v.y*v.y) + (v.z*v.z + v.w*v.w);
  #pragma unroll
  for (int mk = 32; mk >= 1; mk >>= 1) {
    s  += __shfl_xor(s, mk);
    ss += __shfl_xor(ss, mk);
  }
  float mu  = s * (1.0f/256.0f);
  float var = ss * (1.0f/256.0f) - mu*mu;
  float rs  = rsqrtf(var + 1e-5f);
  float4 gg = *(const float4*)(g + lane*4);
  float4 bb = *(const float4*)(b + lane*4);
  float ov[4];
  ov[0] = (v.x - mu) * rs * gg.x + bb.x;
  ov[1] = (v.y - mu) * rs * gg.y + bb.y;
  ov[2] = (v.z - mu) * rs * gg.z + bb.z;
  ov[3] = (v.w - mu) * rs * gg.w + bb.w;
  bfx4 h4, l4;
  #pragma unroll
  for (int u = 0; u < 4; ++u) {
    bfraw hh = f2bf(ov[u]);
    h4[u] = hh;
    l4[u] = f2bf(ov[u] - bf2f(hh));
  }
  bfraw* r = Am + (size_t)row * 768 + lane * 4;
  *(bfx4*)(r)       = h4;
  *(bfx4*)(r + 256) = l4;
  *(bfx4*)(r + 512) = h4;
}

// -------- weight prep: W[k][n] fp32 -> WT'[n][768] bf16 rows [hi|hi|lo] -----
__global__ __launch_bounds__(256) void wprep_qkvg_k(const float* __restrict__ Wq,
    const float* __restrict__ Wk, const float* __restrict__ Wv,
    const float* __restrict__ Wg, bfraw* __restrict__ WT)
{
  int n = blockIdx.x, k = threadIdx.x;
  const float* W = (n < 256) ? Wq : (n < 512) ? Wk : (n < 768) ? Wv : Wg;
  float v = W[k * 256 + (n & 255)];
  bfraw hi = f2bf(v);
  bfraw lo = f2bf(v - bf2f(hi));
  bfraw* r = WT + (size_t)n * 768;
  r[k] = hi; r[256 + k] = hi; r[512 + k] = lo;
}

__global__ __launch_bounds__(256) void wprep_o_k(const float* __restrict__ Wo,
    bfraw* __restrict__ WT)
{
  int n = blockIdx.x, k = threadIdx.x;
  float v = Wo[k * 256 + n];
  bfraw hi = f2bf(v);
  bfraw lo = f2bf(v - bf2f(hi));
  bfraw* r = WT + (size_t)n * 768;
  r[k] = hi; r[256 + k] = hi; r[512 + k] = lo;
}

// ------------- pair LayerNorm (128 wide) + @Wp -> bias[h][i][j] -------------
__global__ __launch_bounds__(256) void ln_pair_bias_k(const float* __restrict__ pair,
    const float* __restrict__ g, const float* __restrict__ b,
    const float* __restrict__ Wp, float* __restrict__ bias)
{
  int row  = blockIdx.x * 4 + (threadIdx.x >> 6);   // i*256 + j
  int lane = threadIdx.x & 63;
  int base = row * 128 + lane * 2;
  float2 v = *(const float2*)(pair + base);
  float s  = v.x + v.y;
  float ss = v.x*v.x + v.y*v.y;
  #pragma unroll
  for (int mk = 32; mk >= 1; mk >>= 1) {
    s  += __shfl_xor(s, mk);
    ss += __shfl_xor(ss, mk);
  }
  float mu  = s * (1.0f/128.0f);
  float var = ss * (1.0f/128.0f) - mu*mu;
  float rs  = rsqrtf(var + 1e-5f);
  float2 gg = *(const float2*)(g + lane*2);
  float2 bb = *(const float2*)(b + lane*2);
  float p0 = (v.x - mu) * rs * gg.x + bb.x;
  float p1 = (v.y - mu) * rs * gg.y + bb.y;
  const float* w0 = Wp + (lane*2) * 8;
  float acc[8];
  #pragma unroll
  for (int hh = 0; hh < 8; ++hh)
    acc[hh] = p0 * w0[hh] + p1 * w0[8 + hh];
  #pragma unroll
  for (int mk = 32; mk >= 1; mk >>= 1)
    #pragma unroll
    for (int hh = 0; hh < 8; ++hh)
      acc[hh] += __shfl_xor(acc[hh], mk);
  #pragma unroll
  for (int hh = 0; hh < 8; ++hh)
    if (lane == hh)
      bias[hh * 65536 + row] = acc[hh];
}

// -------- MFMA GEMM: C[M x N] = A'[M x 768] @ W'T[N x 768]^T ----------------
// mode 0: N=1024, segs 0..2 -> bf16 Q/K/V; seg 3 -> sigmoid(x+bg) fp32 G.
// mode 1: N=256, fp32 out + bo.
__global__ __launch_bounds__(256, 2) void mfma_gemm_k(
    const bfraw* __restrict__ A, const bfraw* __restrict__ BT,
    bfraw* __restrict__ qkv, float* __restrict__ gout,
    const float* __restrict__ bvec, int mode)
{
  __shared__ bfraw As[128 * 32];
  __shared__ bfraw Bs[128 * 32];
  const int t  = threadIdx.x;
  const int bm = blockIdx.x * 128;
  const int bn = blockIdx.y * 128;
  const int lane = t & 63;
  const int w  = t >> 6;
  const int wm = (w & 1) * 64, wn = (w >> 1) * 64;
  const int r16 = lane & 15, q = lane >> 4;

  floatx4 acc[4][4];
  #pragma unroll
  for (int i = 0; i < 4; ++i)
    #pragma unroll
    for (int j = 0; j < 4; ++j)
      acc[i][j] = (floatx4){0.f, 0.f, 0.f, 0.f};

  for (int kb = 0; kb < 768; kb += 32) {
    #pragma unroll
    for (int i2 = 0; i2 < 2; ++i2) {
      int c = i2 * 256 + t;
      int rr = c >> 2, kq = (c & 3) << 3;
      gld16(A  + (size_t)(bm + rr) * 768 + kb + kq, As + c * 8);
      gld16(BT + (size_t)(bn + rr) * 768 + kb + kq, Bs + c * 8);
    }
    __syncthreads();
    short8 af[4], bf[4];
    #pragma unroll
    for (int ti = 0; ti < 4; ++ti)
      af[ti] = *(const short8*)&As[(wm + ti*16 + r16) * 32 + q * 8];
    #pragma unroll
    for (int tj = 0; tj < 4; ++tj)
      bf[tj] = *(const short8*)&Bs[(wn + tj*16 + r16) * 32 + q * 8];
    #pragma unroll
    for (int ti = 0; ti < 4; ++ti)
      #pragma unroll
      for (int tj = 0; tj < 4; ++tj)
        acc[ti][tj] = __builtin_amdgcn_mfma_f32_16x16x32_bf16(
            af[ti], bf[tj], acc[ti][tj], 0, 0, 0);
    __syncthreads();
  }

  if (mode == 0) {
    #pragma unroll
    for (int ti = 0; ti < 4; ++ti) {
      int grow = bm + wm + ti*16 + q*4;
      #pragma unroll
      for (int tj = 0; tj < 4; ++tj) {
        int gcol = bn + wn + tj*16 + r16;
        int seg = gcol >> 8, c2 = gcol & 255;
        if (seg < 3) {
          bfraw* dst = qkv + (size_t)seg * NM + (size_t)grow * 256 + c2;
          #pragma unroll
          for (int r = 0; r < 4; ++r)
            dst[(size_t)r * 256] = f2bf(acc[ti][tj][r]);
        } else {
          float bgv = bvec[c2];
          float* dst = gout + (size_t)grow * 256 + c2;
          #pragma unroll
          for (int r = 0; r < 4; ++r) {
            float xx = acc[ti][tj][r] + bgv;
            dst[(size_t)r * 256] = 1.0f / (1.0f + __expf(-xx));
          }
        }
      }
    }
  } else {
    #pragma unroll
    for (int ti = 0; ti < 4; ++ti) {
      int grow = bm + wm + ti*16 + q*4;
      #pragma unroll
      for (int tj = 0; tj < 4; ++tj) {
        int gcol = bn + wn + tj*16 + r16;
        float bov = bvec[gcol];
        float* dst = gout + (size_t)grow * 256 + gcol;
        #pragma unroll
        for (int r = 0; r < 4; ++r)
          dst[(size_t)r * 256] = acc[ti][tj][r] + bov;
      }
    }
  }
}

// ------------------------- fused attention per (s,h,it) ---------------------
// bf16 Q/K/V inputs; fp32 G; writes gv' pre-split [hi|lo|hi] bf16 [row][768].
__global__ __launch_bounds__(256) void attn_k(
    const bfraw* __restrict__ Q, const bfraw* __restrict__ K,
    const bfraw* __restrict__ V, const float* __restrict__ G,
    const float* __restrict__ bias, bfraw* __restrict__ gv)
{
  __shared__ bfraw KV[256*40];   // union: Kt[32][264] / Vs[256][40]
  __shared__ bfraw Qt[32*72];
  __shared__ bfraw At[256*72];

  const int s = blockIdx.x, h = blockIdx.y, it = blockIdx.z;
  const int t  = threadIdx.x;
  const int ty = t >> 5;
  const int tx = t & 31;

  const size_t qkvb = (size_t)(s*256)*256 + h*32;
  const size_t qtb  = qkvb + (size_t)(it*64)*256;

  { // Q tile (64 x 32) -> Qt[d][il]
    int il = t >> 2, d8 = (t & 3) << 3;
    bfx8 v = *(const bfx8*)(Q + qtb + il*256 + d8);
    #pragma unroll
    for (int u = 0; u < 8; ++u) Qt[(d8+u)*72 + il] = v[u];
  }
  #pragma unroll
  for (int e = 0; e < 4; ++e) { // K (256 x 32) -> Kt[d][j]
    int idx = e*256 + t;
    int j = idx >> 2, d8 = (idx & 3) << 3;
    bfx8 v = *(const bfx8*)(K + qkvb + j*256 + d8);
    #pragma unroll
    for (int u = 0; u < 8; ++u) KV[(d8+u)*264 + j] = v[u];
  }
  __syncthreads();

  float acc[8][8];
  #pragma unroll
  for (int a = 0; a < 8; ++a)
    #pragma unroll
    for (int b = 0; b < 8; ++b) acc[a][b] = 0.f;

  #pragma unroll 4
  for (int kk = 0; kk < 32; ++kk) {
    bfx8 aq = *(const bfx8*)&Qt[kk*72 + ty*8];
    bfx8 bk = *(const bfx8*)&KV[kk*264 + tx*8];
    float qf[8], kf[8];
    #pragma unroll
    for (int u = 0; u < 8; ++u) { qf[u] = bf2f(aq[u]); kf[u] = bf2f(bk[u]); }
    #pragma unroll
    for (int a = 0; a < 8; ++a)
      #pragma unroll
      for (int b = 0; b < 8; ++b)
        acc[a][b] = fmaf(qf[a], kf[b], acc[a][b]);
  }

  const float scale = 0.17677669529663687f;
  const float* bp = bias + h*65536;
  float l[8];
  #pragma unroll
  for (int a = 0; a < 8; ++a) {
    int i = it*64 + ty*8 + a;
    const float* bi = bp + i*256 + tx*8;
    float4 b0 = *(const float4*)bi;
    float4 b1 = *(const float4*)(bi + 4);
    acc[a][0] = __expf(fmaf(acc[a][0], scale, b0.x));
    acc[a][1] = __expf(fmaf(acc[a][1], scale, b0.y));
    acc[a][2] = __expf(fmaf(acc[a][2], scale, b0.z));
    acc[a][3] = __expf(fmaf(acc[a][3], scale, b0.w));
    acc[a][4] = __expf(fmaf(acc[a][4], scale, b1.x));
    acc[a][5] = __expf(fmaf(acc[a][5], scale, b1.y));
    acc[a][6] = __expf(fmaf(acc[a][6], scale, b1.z));
    acc[a][7] = __expf(fmaf(acc[a][7], scale, b1.w));
    l[a] = ((acc[a][0]+acc[a][1])+(acc[a][2]+acc[a][3]))
         + ((acc[a][4]+acc[a][5])+(acc[a][6]+acc[a][7]));
  }
  #pragma unroll
  for (int mk = 1; mk <= 16; mk <<= 1)
    #pragma unroll
    for (int a = 0; a < 8; ++a)
      l[a] += __shfl_xor(l[a], mk);

  #pragma unroll
  for (int b = 0; b < 8; ++b) {
    int j  = tx*8 + b;
    int g2 = (ty + tx + (tx >> 2)) & 7;
    bfx8 pk;
    #pragma unroll
    for (int a = 0; a < 8; ++a) pk[a] = f2bf(acc[a][b]);
    *(bfx8*)&At[j*72 + g2*8] = pk;
  }
  __syncthreads();

  #pragma unroll
  for (int e = 0; e < 4; ++e) { // V -> Vs[j][d]
    int idx = e*256 + t;
    int j = idx >> 2, d8 = (idx & 3) << 3;
    bfx8 v = *(const bfx8*)(V + qkvb + j*256 + d8);
    *(bfx8*)&KV[j*40 + d8] = v;
  }
  __syncthreads();

  const int dg = tx & 3;
  const int jq = tx >> 2;
  float vacc[8][8];
  #pragma unroll
  for (int a = 0; a < 8; ++a)
    #pragma unroll
    for (int d = 0; d < 8; ++d) vacc[a][d] = 0.f;

  #pragma unroll 4
  for (int jj = 0; jj < 32; ++jj) {
    int j  = (jj << 3) + jq;
    int g2 = (ty + jj + (jj >> 2)) & 7;
    bfx8 ap = *(const bfx8*)&At[j*72 + g2*8];
    bfx8 vp = *(const bfx8*)&KV[j*40 + dg*8];
    float af[8], vf[8];
    #pragma unroll
    for (int u = 0; u < 8; ++u) { af[u] = bf2f(ap[u]); vf[u] = bf2f(vp[u]); }
    #pragma unroll
    for (int a = 0; a < 8; ++a)
      #pragma unroll
      for (int d = 0; d < 8; ++d)
        vacc[a][d] = fmaf(af[a], vf[d], vacc[a][d]);
  }
  #pragma unroll
  for (int mk = 4; mk <= 16; mk <<= 1)
    #pragma unroll
    for (int a = 0; a < 8; ++a)
      #pragma unroll
      for (int d = 0; d < 8; ++d)
        vacc[a][d] += __shfl_xor(vacc[a][d], mk);

  #pragma unroll
  for (int a = 0; a < 8; ++a) {
    if (jq == a) {
      float invl = 1.0f / l[a];
      int i = it*64 + ty*8 + a;
      size_t gb = ((size_t)(s*256) + i)*256 + h*32 + dg*8;
      float4 g0 = *(const float4*)(G + gb);
      float4 g1 = *(const float4*)(G + gb + 4);
      float o[8];
      o[0] = g0.x * vacc[a][0] * invl;
      o[1] = g0.y * vacc[a][1] * invl;
      o[2] = g0.z * vacc[a][2] * invl;
      o[3] = g0.w * vacc[a][3] * invl;
      o[4] = g1.x * vacc[a][4] * invl;
      o[5] = g1.y * vacc[a][5] * invl;
      o[6] = g1.z * vacc[a][6] * invl;
      o[7] = g1.w * vacc[a][7] * invl;
      bfx8 h8, l8;
      #pragma unroll
      for (int u = 0; u < 8; ++u) {
        bfraw hh = f2bf(o[u]);
        h8[u] = hh;
        l8[u] = f2bf(o[u] - bf2f(hh));
      }
      bfraw* gr = gv + ((size_t)(s*256) + i)*768 + h*32 + dg*8;
      *(bfx8*)(gr)       = h8;
      *(bfx8*)(gr + 256) = l8;
      *(bfx8*)(gr + 512) = h8;
    }
  }
}

extern "C" void kernel_launch(void* const* d_in, const int* in_sizes, int n_in,
                              void* d_out, int out_size, void* d_ws, size_t ws_size,
                              hipStream_t stream) {
  const float* msa    = (const float*)d_in[0];
  const float* pair   = (const float*)d_in[1];
  const float* ln_m_g = (const float*)d_in[2];
  const float* ln_m_b = (const float*)d_in[3];
  const float* ln_p_g = (const float*)d_in[4];
  const float* ln_p_b = (const float*)d_in[5];
  const float* Wq     = (const float*)d_in[6];
  const float* Wk     = (const float*)d_in[7];
  const float* Wv     = (const float*)d_in[8];
  const float* Wp     = (const float*)d_in[9];
  const float* Wg     = (const float*)d_in[10];
  const float* bg     = (const float*)d_in[11];
  const float* Wo     = (const float*)d_in[12];
  const float* bo     = (const float*)d_in[13];
  float* out = (float*)d_out;

  char* wsb = (char*)d_ws;
  bfraw* Am      = (bfraw*)(wsb);                    // 48 MB  [32768][768]
  bfraw* QKV16   = (bfraw*)(wsb + 50331648);         // 48 MB  3 x [32768][256]
  float* Gb      = (float*)(wsb + 100663296);        // 32 MB  [32768][256]
  float* biasb   = (float*)(wsb + 134217728);        //  2 MB  [8][65536]
  bfraw* WqkvgT  = (bfraw*)(wsb + 136314880);        // 1.5 MB [1024][768]
  bfraw* WoT     = (bfraw*)(wsb + 137887744);        // .4 MB  [256][768]
  bfraw* gvp     = Am;                               // alias: Am dead after QKVG

  ln_msa_k<<<8192, 256, 0, stream>>>(msa, ln_m_g, ln_m_b, Am);
  wprep_qkvg_k<<<1024, 256, 0, stream>>>(Wq, Wk, Wv, Wg, WqkvgT);
  wprep_o_k<<<256, 256, 0, stream>>>(Wo, WoT);
  ln_pair_bias_k<<<16384, 256, 0, stream>>>(pair, ln_p_g, ln_p_b, Wp, biasb);

  mfma_gemm_k<<<dim3(256, 8), 256, 0, stream>>>(Am, WqkvgT, QKV16, Gb, bg, 0);

  attn_k<<<dim3(128, 8, 4), 256, 0, stream>>>(QKV16, QKV16 + NM, QKV16 + 2*NM,
                                              Gb, biasb, gvp);

  mfma_gemm_k<<<dim3(256, 2), 256, 0, stream>>>(gvp, WoT, nullptr, out, bo, 1);
}

// Round 3
// 394.409 us; speedup vs baseline: 1.5906x; 1.0860x over previous
//
#include <hip/hip_runtime.h>

// MSARowAttentionWithPairBias — round 3: MFMA flash-attention.
// GEMMs as round 2 (split-bf16 MFMA). attn_k rewritten:
//   per (s,h) block, 4 waves x 64 i-rows. S^T = K.Q^T (C col = i -> coalesced
//   transposed-bias loads), exp in-regs, P -> per-wave swizzled LDS,
//   O^T = V^T.P^T with V^T staged in LDS. G stored transposed by the QKVG
//   GEMM epilogue for coalesced epilogue reads.
//
// ws: Am/gv' 48M | QKV16 48M | Gt 32M | biasT 2M | WqkvgT 1.5M | WoT .4M

typedef unsigned short bfraw;
typedef bfraw bfx8 __attribute__((ext_vector_type(8)));
typedef bfraw bfx4 __attribute__((ext_vector_type(4)));
typedef short short8 __attribute__((ext_vector_type(8)));
typedef float floatx4 __attribute__((ext_vector_type(4)));

#define NM 8388608u            // 32768*256 elements

__device__ __forceinline__ float bf2f(bfraw u) {
  return __uint_as_float(((unsigned)u) << 16);
}
__device__ __forceinline__ bfraw f2bf(float f) {
  unsigned x = __float_as_uint(f);
  unsigned r = x + 0x7fffu + ((x >> 16) & 1u);   // RNE
  return (bfraw)(r >> 16);
}

__device__ __forceinline__ void gld16(const bfraw* g, bfraw* l) {
  __builtin_amdgcn_global_load_lds(
      (const __attribute__((address_space(1))) unsigned int*)g,
      (__attribute__((address_space(3))) unsigned int*)l, 16, 0, 0);
}

// -------- LayerNorm msa rows (256 wide) -> A' = [hi|lo|hi] bf16 [row][768] --
__global__ __launch_bounds__(256) void ln_msa_k(const float* __restrict__ x,
    const float* __restrict__ g, const float* __restrict__ b,
    bfraw* __restrict__ Am)
{
  int row  = blockIdx.x * 4 + (threadIdx.x >> 6);
  int lane = threadIdx.x & 63;
  int base = row * 256 + lane * 4;
  float4 v = *(const float4*)(x + base);
  float s  = (v.x + v.y) + (v.z + v.w);
  float ss = (v.x*v.x + v.y*v.y) + (v.z*v.z + v.w*v.w);
  #pragma unroll
  for (int mk = 32; mk >= 1; mk >>= 1) {
    s  += __shfl_xor(s, mk);
    ss += __shfl_xor(ss, mk);
  }
  float mu  = s * (1.0f/256.0f);
  float var = ss * (1.0f/256.0f) - mu*mu;
  float rs  = rsqrtf(var + 1e-5f);
  float4 gg = *(const float4*)(g + lane*4);
  float4 bb = *(const float4*)(b + lane*4);
  float ov[4];
  ov[0] = (v.x - mu) * rs * gg.x + bb.x;
  ov[1] = (v.y - mu) * rs * gg.y + bb.y;
  ov[2] = (v.z - mu) * rs * gg.z + bb.z;
  ov[3] = (v.w - mu) * rs * gg.w + bb.w;
  bfx4 h4, l4;
  #pragma unroll
  for (int u = 0; u < 4; ++u) {
    bfraw hh = f2bf(ov[u]);
    h4[u] = hh;
    l4[u] = f2bf(ov[u] - bf2f(hh));
  }
  bfraw* r = Am + (size_t)row * 768 + lane * 4;
  *(bfx4*)(r)       = h4;
  *(bfx4*)(r + 256) = l4;
  *(bfx4*)(r + 512) = h4;
}

// -------- weight prep: W[k][n] fp32 -> WT'[n][768] bf16 rows [hi|hi|lo] -----
__global__ __launch_bounds__(256) void wprep_qkvg_k(const float* __restrict__ Wq,
    const float* __restrict__ Wk, const float* __restrict__ Wv,
    const float* __restrict__ Wg, bfraw* __restrict__ WT)
{
  int n = blockIdx.x, k = threadIdx.x;
  const float* W = (n < 256) ? Wq : (n < 512) ? Wk : (n < 768) ? Wv : Wg;
  float v = W[k * 256 + (n & 255)];
  bfraw hi = f2bf(v);
  bfraw lo = f2bf(v - bf2f(hi));
  bfraw* r = WT + (size_t)n * 768;
  r[k] = hi; r[256 + k] = hi; r[512 + k] = lo;
}

__global__ __launch_bounds__(256) void wprep_o_k(const float* __restrict__ Wo,
    bfraw* __restrict__ WT)
{
  int n = blockIdx.x, k = threadIdx.x;
  float v = Wo[k * 256 + n];
  bfraw hi = f2bf(v);
  bfraw lo = f2bf(v - bf2f(hi));
  bfraw* r = WT + (size_t)n * 768;
  r[k] = hi; r[256 + k] = hi; r[512 + k] = lo;
}

// ------- pair LayerNorm (128 wide) + @Wp -> biasT[h][j][i] (transposed) -----
__global__ __launch_bounds__(256) void ln_pair_bias_k(const float* __restrict__ pair,
    const float* __restrict__ g, const float* __restrict__ b,
    const float* __restrict__ Wp, float* __restrict__ biasT)
{
  int row  = blockIdx.x * 4 + (threadIdx.x >> 6);   // i*256 + j
  int lane = threadIdx.x & 63;
  int base = row * 128 + lane * 2;
  float2 v = *(const float2*)(pair + base);
  float s  = v.x + v.y;
  float ss = v.x*v.x + v.y*v.y;
  #pragma unroll
  for (int mk = 32; mk >= 1; mk >>= 1) {
    s  += __shfl_xor(s, mk);
    ss += __shfl_xor(ss, mk);
  }
  float mu  = s * (1.0f/128.0f);
  float var = ss * (1.0f/128.0f) - mu*mu;
  float rs  = rsqrtf(var + 1e-5f);
  float2 gg = *(const float2*)(g + lane*2);
  float2 bb = *(const float2*)(b + lane*2);
  float p0 = (v.x - mu) * rs * gg.x + bb.x;
  float p1 = (v.y - mu) * rs * gg.y + bb.y;
  const float* w0 = Wp + (lane*2) * 8;
  float acc[8];
  #pragma unroll
  for (int hh = 0; hh < 8; ++hh)
    acc[hh] = p0 * w0[hh] + p1 * w0[8 + hh];
  #pragma unroll
  for (int mk = 32; mk >= 1; mk >>= 1)
    #pragma unroll
    for (int hh = 0; hh < 8; ++hh)
      acc[hh] += __shfl_xor(acc[hh], mk);
  // transposed store: biasT[h][j*256 + i], row = i*256 + j
  #pragma unroll
  for (int hh = 0; hh < 8; ++hh)
    if (lane == hh)
      biasT[hh * 65536 + (row & 255) * 256 + (row >> 8)] = acc[hh];
}

// -------- MFMA GEMM: C[M x N] = A'[M x 768] @ W'T[N x 768]^T ----------------
// mode 0: N=1024, segs 0..2 -> bf16 Q/K/V; seg 3 -> sigmoid -> Gt TRANSPOSED
//         fp32 [256][32768].
// mode 1: N=256, fp32 out + bo.
__global__ __launch_bounds__(256, 2) void mfma_gemm_k(
    const bfraw* __restrict__ A, const bfraw* __restrict__ BT,
    bfraw* __restrict__ qkv, float* __restrict__ gout,
    const float* __restrict__ bvec, int mode)
{
  __shared__ bfraw As[128 * 32];
  __shared__ bfraw Bs[128 * 32];
  const int t  = threadIdx.x;
  const int bm = blockIdx.x * 128;
  const int bn = blockIdx.y * 128;
  const int lane = t & 63;
  const int w  = t >> 6;
  const int wm = (w & 1) * 64, wn = (w >> 1) * 64;
  const int r16 = lane & 15, q = lane >> 4;

  floatx4 acc[4][4];
  #pragma unroll
  for (int i = 0; i < 4; ++i)
    #pragma unroll
    for (int j = 0; j < 4; ++j)
      acc[i][j] = (floatx4){0.f, 0.f, 0.f, 0.f};

  for (int kb = 0; kb < 768; kb += 32) {
    #pragma unroll
    for (int i2 = 0; i2 < 2; ++i2) {
      int c = i2 * 256 + t;
      int rr = c >> 2, kq = (c & 3) << 3;
      gld16(A  + (size_t)(bm + rr) * 768 + kb + kq, As + c * 8);
      gld16(BT + (size_t)(bn + rr) * 768 + kb + kq, Bs + c * 8);
    }
    __syncthreads();
    short8 af[4], bf[4];
    #pragma unroll
    for (int ti = 0; ti < 4; ++ti)
      af[ti] = *(const short8*)&As[(wm + ti*16 + r16) * 32 + q * 8];
    #pragma unroll
    for (int tj = 0; tj < 4; ++tj)
      bf[tj] = *(const short8*)&Bs[(wn + tj*16 + r16) * 32 + q * 8];
    #pragma unroll
    for (int ti = 0; ti < 4; ++ti)
      #pragma unroll
      for (int tj = 0; tj < 4; ++tj)
        acc[ti][tj] = __builtin_amdgcn_mfma_f32_16x16x32_bf16(
            af[ti], bf[tj], acc[ti][tj], 0, 0, 0);
    __syncthreads();
  }

  if (mode == 0) {
    #pragma unroll
    for (int ti = 0; ti < 4; ++ti) {
      int grow = bm + wm + ti*16 + q*4;
      #pragma unroll
      for (int tj = 0; tj < 4; ++tj) {
        int gcol = bn + wn + tj*16 + r16;
        int seg = gcol >> 8, c2 = gcol & 255;
        if (seg < 3) {
          bfraw* dst = qkv + (size_t)seg * NM + (size_t)grow * 256 + c2;
          #pragma unroll
          for (int r = 0; r < 4; ++r)
            dst[(size_t)r * 256] = f2bf(acc[ti][tj][r]);
        } else {
          float bgv = bvec[c2];
          float4 o;
          o.x = 1.0f / (1.0f + __expf(-(acc[ti][tj][0] + bgv)));
          o.y = 1.0f / (1.0f + __expf(-(acc[ti][tj][1] + bgv)));
          o.z = 1.0f / (1.0f + __expf(-(acc[ti][tj][2] + bgv)));
          o.w = 1.0f / (1.0f + __expf(-(acc[ti][tj][3] + bgv)));
          // Gt transposed: [d=c2][row], 4 consecutive rows -> float4
          *(float4*)(gout + (size_t)c2 * 32768 + grow) = o;
        }
      }
    }
  } else {
    #pragma unroll
    for (int ti = 0; ti < 4; ++ti) {
      int grow = bm + wm + ti*16 + q*4;
      #pragma unroll
      for (int tj = 0; tj < 4; ++tj) {
        int gcol = bn + wn + tj*16 + r16;
        float bov = bvec[gcol];
        float* dst = gout + (size_t)grow * 256 + gcol;
        #pragma unroll
        for (int r = 0; r < 4; ++r)
          dst[(size_t)r * 256] = acc[ti][tj][r] + bov;
      }
    }
  }
}

// ---------------- MFMA flash attention: one block per (s,h) -----------------
// 4 waves x 64 i. S^T = K.Q^T; P -> per-wave LDS (XOR swizzle); O^T = V^T.P^T.
__global__ __launch_bounds__(256) void attn_k(
    const bfraw* __restrict__ Q, const bfraw* __restrict__ K,
    const bfraw* __restrict__ V, const float* __restrict__ Gt,
    const float* __restrict__ biasT, bfraw* __restrict__ gv)
{
  __shared__ bfraw Vt[32 * 256];       // [d][j], col j ^ ((d&7)<<3)
  __shared__ bfraw Pb[4][64 * 64];     // per-wave [i_local][j_local], swizzled

  const int s = blockIdx.x, h = blockIdx.y;
  const int t = threadIdx.x;
  const int w = t >> 6, lane = t & 63;
  const int r16 = lane & 15, q = lane >> 4;
  const size_t base = ((size_t)s * 256) * 256 + h * 32;   // + row*256 + d

  // stage V -> Vt (transposed, swizzled)
  #pragma unroll
  for (int e = 0; e < 4; ++e) {
    int idx = e * 256 + t;
    int j = idx >> 2, d8 = (idx & 3) << 3;
    bfx8 v = *(const bfx8*)(V + base + (size_t)j * 256 + d8);
    #pragma unroll
    for (int u = 0; u < 8; ++u) {
      int d = d8 + u;
      Vt[d * 256 + (j ^ ((d & 7) << 3))] = v[u];
    }
  }
  __syncthreads();

  const int ibase = w * 64;
  // persistent Q B-frags: n = i = ibase + it*16 + r16, k = q*8..q*8+7
  short8 qf[4];
  #pragma unroll
  for (int it = 0; it < 4; ++it)
    qf[it] = *(const short8*)(Q + base + (size_t)(ibase + it*16 + r16) * 256 + q*8);

  floatx4 accO[2][4];                  // [dt][it], O^T tiles
  #pragma unroll
  for (int dt = 0; dt < 2; ++dt)
    #pragma unroll
    for (int it = 0; it < 4; ++it)
      accO[dt][it] = (floatx4){0.f, 0.f, 0.f, 0.f};
  float lp[4] = {0.f, 0.f, 0.f, 0.f};

  bfraw* pb = &Pb[w][0];
  const float scale = 0.17677669529663687f;   // 1/sqrt(32)
  const float* bp = biasT + h * 65536;        // [j][i]

  for (int jc = 0; jc < 4; ++jc) {
    const int j0 = jc * 64;
    // K A-frags: m = j = j0 + jt*16 + r16, k = q*8..
    short8 kf[4];
    #pragma unroll
    for (int jt = 0; jt < 4; ++jt)
      kf[jt] = *(const short8*)(K + base + (size_t)(j0 + jt*16 + r16) * 256 + q*8);

    floatx4 sc[4][4];                  // [jt][it], S^T tiles: row=j, col=i
    #pragma unroll
    for (int jt = 0; jt < 4; ++jt)
      #pragma unroll
      for (int it = 0; it < 4; ++it)
        sc[jt][it] = (floatx4){0.f, 0.f, 0.f, 0.f};
    #pragma unroll
    for (int jt = 0; jt < 4; ++jt)
      #pragma unroll
      for (int it = 0; it < 4; ++it)
        sc[jt][it] = __builtin_amdgcn_mfma_f32_16x16x32_bf16(
            kf[jt], qf[it], sc[jt][it], 0, 0, 0);

    // bias + exp + row-sum partials + pack P to LDS
    #pragma unroll
    for (int jt = 0; jt < 4; ++jt) {
      #pragma unroll
      for (int it = 0; it < 4; ++it) {
        int i  = ibase + it*16 + r16;
        int jb = j0 + jt*16 + q*4;
        int il = it*16 + r16;
        bfx4 p4;
        #pragma unroll
        for (int r = 0; r < 4; ++r) {
          float bv = bp[(jb + r) * 256 + i];
          float x  = __expf(fmaf(sc[jt][it][r], scale, bv));
          lp[it] += x;
          p4[r] = f2bf(x);
        }
        int col = (jt*16 + q*4) ^ ((il & 7) << 3);
        *(bfx4*)&pb[il * 64 + col] = p4;
      }
    }

    // O^T += V^T(chunk) . P^T(chunk), K=64 -> 2 k-steps
    #pragma unroll
    for (int kk = 0; kk < 2; ++kk) {
      short8 vf[2], pf[4];
      #pragma unroll
      for (int dt = 0; dt < 2; ++dt) {
        int d = dt*16 + r16;
        vf[dt] = *(const short8*)&Vt[d * 256 + ((j0 + kk*32 + q*8) ^ ((d & 7) << 3))];
      }
      #pragma unroll
      for (int it = 0; it < 4; ++it) {
        int il = it*16 + r16;
        pf[it] = *(const short8*)&pb[il * 64 + ((kk*32 + q*8) ^ ((il & 7) << 3))];
      }
      #pragma unroll
      for (int dt = 0; dt < 2; ++dt)
        #pragma unroll
        for (int it = 0; it < 4; ++it)
          accO[dt][it] = __builtin_amdgcn_mfma_f32_16x16x32_bf16(
              vf[dt], pf[it], accO[dt][it], 0, 0, 0);
    }
  }

  // full row sums: reduce over q-groups (lanes with same r16)
  #pragma unroll
  for (int mk = 16; mk <= 32; mk <<= 1)
    #pragma unroll
    for (int it = 0; it < 4; ++it)
      lp[it] += __shfl_xor(lp[it], mk);

  // epilogue: O^T C-layout -> lane col i = r16, row d = dt*16 + q*4 + r
  #pragma unroll
  for (int it = 0; it < 4; ++it) {
    float invl = 1.0f / lp[it];
    int i = ibase + it*16 + r16;
    size_t row = (size_t)s * 256 + i;
    #pragma unroll
    for (int dt = 0; dt < 2; ++dt) {
      int d0 = h*32 + dt*16 + q*4;
      bfx4 h4, l4;
      #pragma unroll
      for (int r = 0; r < 4; ++r) {
        float g = Gt[(size_t)(d0 + r) * 32768 + row];
        float o = g * accO[dt][it][r] * invl;
        bfraw hh = f2bf(o);
        h4[r] = hh;
        l4[r] = f2bf(o - bf2f(hh));
      }
      bfraw* gr = gv + row * 768 + d0;
      *(bfx4*)(gr)       = h4;
      *(bfx4*)(gr + 256) = l4;
      *(bfx4*)(gr + 512) = h4;
    }
  }
}

extern "C" void kernel_launch(void* const* d_in, const int* in_sizes, int n_in,
                              void* d_out, int out_size, void* d_ws, size_t ws_size,
                              hipStream_t stream) {
  const float* msa    = (const float*)d_in[0];
  const float* pair   = (const float*)d_in[1];
  const float* ln_m_g = (const float*)d_in[2];
  const float* ln_m_b = (const float*)d_in[3];
  const float* ln_p_g = (const float*)d_in[4];
  const float* ln_p_b = (const float*)d_in[5];
  const float* Wq     = (const float*)d_in[6];
  const float* Wk     = (const float*)d_in[7];
  const float* Wv     = (const float*)d_in[8];
  const float* Wp     = (const float*)d_in[9];
  const float* Wg     = (const float*)d_in[10];
  const float* bg     = (const float*)d_in[11];
  const float* Wo     = (const float*)d_in[12];
  const float* bo     = (const float*)d_in[13];
  float* out = (float*)d_out;

  char* wsb = (char*)d_ws;
  bfraw* Am      = (bfraw*)(wsb);                    // 48 MB  [32768][768]
  bfraw* QKV16   = (bfraw*)(wsb + 50331648);         // 48 MB  3 x [32768][256]
  float* Gtb     = (float*)(wsb + 100663296);        // 32 MB  [256][32768]
  float* biasT   = (float*)(wsb + 134217728);        //  2 MB  [8][65536] (j-major)
  bfraw* WqkvgT  = (bfraw*)(wsb + 136314880);        // 1.5 MB [1024][768]
  bfraw* WoT     = (bfraw*)(wsb + 137887744);        // .4 MB  [256][768]
  bfraw* gvp     = Am;                               // alias: Am dead after QKVG

  ln_msa_k<<<8192, 256, 0, stream>>>(msa, ln_m_g, ln_m_b, Am);
  wprep_qkvg_k<<<1024, 256, 0, stream>>>(Wq, Wk, Wv, Wg, WqkvgT);
  wprep_o_k<<<256, 256, 0, stream>>>(Wo, WoT);
  ln_pair_bias_k<<<16384, 256, 0, stream>>>(pair, ln_p_g, ln_p_b, Wp, biasT);

  mfma_gemm_k<<<dim3(256, 8), 256, 0, stream>>>(Am, WqkvgT, QKV16, Gtb, bg, 0);

  attn_k<<<dim3(128, 8), 256, 0, stream>>>(QKV16, QKV16 + NM, QKV16 + 2*NM,
                                           Gtb, biasT, gvp);

  mfma_gemm_k<<<dim3(256, 2), 256, 0, stream>>>(gvp, WoT, nullptr, out, bo, 1);
}

// Round 4
// 314.630 us; speedup vs baseline: 1.9939x; 1.2536x over previous
//
#include <hip/hip_runtime.h>

// MSARowAttentionWithPairBias — round 4: latency attack on attn.
//  * bias in fragment order [h][j>>2][i][j&3] -> float4 loads (was 4x scalar
//    stride-1KB), coalesced 256B/instr.
//  * attn P-chunk 32 j (8 iters): Pb 16KB, LDS 32KB total, launch_bounds(256,4)
//    -> 4 blocks/CU (was 3).
//  * GEMM epilogues compute the transposed product (swap MFMA operands):
//    lane holds 4 consecutive n -> QKV packed bfx4 stores, G fragment-ordered
//    [d>>2][row][d&3] float4 stores (+float4 attn loads), out float4 stores.
//
// ws: Am/gv' 48M | QKV16 48M | Gf 32M | biasF 2M | WqkvgT 1.5M | WoT .4M

typedef unsigned short bfraw;
typedef bfraw bfx8 __attribute__((ext_vector_type(8)));
typedef bfraw bfx4 __attribute__((ext_vector_type(4)));
typedef short short8 __attribute__((ext_vector_type(8)));
typedef float floatx4 __attribute__((ext_vector_type(4)));

#define NM 8388608u            // 32768*256 elements

__device__ __forceinline__ float bf2f(bfraw u) {
  return __uint_as_float(((unsigned)u) << 16);
}
__device__ __forceinline__ bfraw f2bf(float f) {
  unsigned x = __float_as_uint(f);
  unsigned r = x + 0x7fffu + ((x >> 16) & 1u);   // RNE
  return (bfraw)(r >> 16);
}

__device__ __forceinline__ void gld16(const bfraw* g, bfraw* l) {
  __builtin_amdgcn_global_load_lds(
      (const __attribute__((address_space(1))) unsigned int*)g,
      (__attribute__((address_space(3))) unsigned int*)l, 16, 0, 0);
}

// -------- LayerNorm msa rows (256 wide) -> A' = [hi|lo|hi] bf16 [row][768] --
__global__ __launch_bounds__(256) void ln_msa_k(const float* __restrict__ x,
    const float* __restrict__ g, const float* __restrict__ b,
    bfraw* __restrict__ Am)
{
  int row  = blockIdx.x * 4 + (threadIdx.x >> 6);
  int lane = threadIdx.x & 63;
  int base = row * 256 + lane * 4;
  float4 v = *(const float4*)(x + base);
  float s  = (v.x + v.y) + (v.z + v.w);
  float ss = (v.x*v.x + v.y*v.y) + (v.z*v.z + v.w*v.w);
  #pragma unroll
  for (int mk = 32; mk >= 1; mk >>= 1) {
    s  += __shfl_xor(s, mk);
    ss += __shfl_xor(ss, mk);
  }
  float mu  = s * (1.0f/256.0f);
  float var = ss * (1.0f/256.0f) - mu*mu;
  float rs  = rsqrtf(var + 1e-5f);
  float4 gg = *(const float4*)(g + lane*4);
  float4 bb = *(const float4*)(b + lane*4);
  float ov[4];
  ov[0] = (v.x - mu) * rs * gg.x + bb.x;
  ov[1] = (v.y - mu) * rs * gg.y + bb.y;
  ov[2] = (v.z - mu) * rs * gg.z + bb.z;
  ov[3] = (v.w - mu) * rs * gg.w + bb.w;
  bfx4 h4, l4;
  #pragma unroll
  for (int u = 0; u < 4; ++u) {
    bfraw hh = f2bf(ov[u]);
    h4[u] = hh;
    l4[u] = f2bf(ov[u] - bf2f(hh));
  }
  bfraw* r = Am + (size_t)row * 768 + lane * 4;
  *(bfx4*)(r)       = h4;
  *(bfx4*)(r + 256) = l4;
  *(bfx4*)(r + 512) = h4;
}

// -------- weight prep: W[k][n] fp32 -> WT'[n][768] bf16 rows [hi|hi|lo] -----
__global__ __launch_bounds__(256) void wprep_qkvg_k(const float* __restrict__ Wq,
    const float* __restrict__ Wk, const float* __restrict__ Wv,
    const float* __restrict__ Wg, bfraw* __restrict__ WT)
{
  int n = blockIdx.x, k = threadIdx.x;
  const float* W = (n < 256) ? Wq : (n < 512) ? Wk : (n < 768) ? Wv : Wg;
  float v = W[k * 256 + (n & 255)];
  bfraw hi = f2bf(v);
  bfraw lo = f2bf(v - bf2f(hi));
  bfraw* r = WT + (size_t)n * 768;
  r[k] = hi; r[256 + k] = hi; r[512 + k] = lo;
}

__global__ __launch_bounds__(256) void wprep_o_k(const float* __restrict__ Wo,
    bfraw* __restrict__ WT)
{
  int n = blockIdx.x, k = threadIdx.x;
  float v = Wo[k * 256 + n];
  bfraw hi = f2bf(v);
  bfraw lo = f2bf(v - bf2f(hi));
  bfraw* r = WT + (size_t)n * 768;
  r[k] = hi; r[256 + k] = hi; r[512 + k] = lo;
}

// --- pair LayerNorm (128 wide) + @Wp -> biasF[h][j>>2][i][j&3] (frag order) -
__global__ __launch_bounds__(256) void ln_pair_bias_k(const float* __restrict__ pair,
    const float* __restrict__ g, const float* __restrict__ b,
    const float* __restrict__ Wp, float* __restrict__ biasF)
{
  int row  = blockIdx.x * 4 + (threadIdx.x >> 6);   // i*256 + j
  int lane = threadIdx.x & 63;
  int base = row * 128 + lane * 2;
  float2 v = *(const float2*)(pair + base);
  float s  = v.x + v.y;
  float ss = v.x*v.x + v.y*v.y;
  #pragma unroll
  for (int mk = 32; mk >= 1; mk >>= 1) {
    s  += __shfl_xor(s, mk);
    ss += __shfl_xor(ss, mk);
  }
  float mu  = s * (1.0f/128.0f);
  float var = ss * (1.0f/128.0f) - mu*mu;
  float rs  = rsqrtf(var + 1e-5f);
  float2 gg = *(const float2*)(g + lane*2);
  float2 bb = *(const float2*)(b + lane*2);
  float p0 = (v.x - mu) * rs * gg.x + bb.x;
  float p1 = (v.y - mu) * rs * gg.y + bb.y;
  const float* w0 = Wp + (lane*2) * 8;
  float acc[8];
  #pragma unroll
  for (int hh = 0; hh < 8; ++hh)
    acc[hh] = p0 * w0[hh] + p1 * w0[8 + hh];
  #pragma unroll
  for (int mk = 32; mk >= 1; mk >>= 1)
    #pragma unroll
    for (int hh = 0; hh < 8; ++hh)
      acc[hh] += __shfl_xor(acc[hh], mk);
  // frag-order store: row = i*256 + j -> [h][j>>2][i][j&3]
  int i = row >> 8, j = row & 255;
  #pragma unroll
  for (int hh = 0; hh < 8; ++hh)
    if (lane == hh)
      biasF[hh * 65536 + (j >> 2) * 1024 + i * 4 + (j & 3)] = acc[hh];
}

// -------- MFMA GEMM (transposed product): C = A'[Mx768] @ W'T[Nx768]^T ------
// acc[ti][tj] = mfma(bf[tj], af[ti]) -> lane: m = ..+r16, n = ..+q*4+r.
// mode 0: N=1024, segs 0..2 -> bf16 Q/K/V packed bfx4; seg 3 -> sigmoid ->
//         Gf fragment-ordered [d>>2][row][d&3] float4.
// mode 1: N=256, fp32 out + bo, float4 stores.
__global__ __launch_bounds__(256, 2) void mfma_gemm_k(
    const bfraw* __restrict__ A, const bfraw* __restrict__ BT,
    bfraw* __restrict__ qkv, float* __restrict__ gout,
    const float* __restrict__ bvec, int mode)
{
  __shared__ bfraw As[128 * 32];
  __shared__ bfraw Bs[128 * 32];
  const int t  = threadIdx.x;
  const int bm = blockIdx.x * 128;
  const int bn = blockIdx.y * 128;
  const int lane = t & 63;
  const int w  = t >> 6;
  const int wm = (w & 1) * 64, wn = (w >> 1) * 64;
  const int r16 = lane & 15, q = lane >> 4;

  floatx4 acc[4][4];
  #pragma unroll
  for (int i = 0; i < 4; ++i)
    #pragma unroll
    for (int j = 0; j < 4; ++j)
      acc[i][j] = (floatx4){0.f, 0.f, 0.f, 0.f};

  for (int kb = 0; kb < 768; kb += 32) {
    #pragma unroll
    for (int i2 = 0; i2 < 2; ++i2) {
      int c = i2 * 256 + t;
      int rr = c >> 2, kq = (c & 3) << 3;
      gld16(A  + (size_t)(bm + rr) * 768 + kb + kq, As + c * 8);
      gld16(BT + (size_t)(bn + rr) * 768 + kb + kq, Bs + c * 8);
    }
    __syncthreads();
    short8 af[4], bf[4];
    #pragma unroll
    for (int ti = 0; ti < 4; ++ti)
      af[ti] = *(const short8*)&As[(wm + ti*16 + r16) * 32 + q * 8];
    #pragma unroll
    for (int tj = 0; tj < 4; ++tj)
      bf[tj] = *(const short8*)&Bs[(wn + tj*16 + r16) * 32 + q * 8];
    #pragma unroll
    for (int ti = 0; ti < 4; ++ti)
      #pragma unroll
      for (int tj = 0; tj < 4; ++tj)
        acc[ti][tj] = __builtin_amdgcn_mfma_f32_16x16x32_bf16(
            bf[tj], af[ti], acc[ti][tj], 0, 0, 0);   // transposed product
    __syncthreads();
  }

  if (mode == 0) {
    #pragma unroll
    for (int ti = 0; ti < 4; ++ti) {
      int m = bm + wm + ti*16 + r16;
      #pragma unroll
      for (int tj = 0; tj < 4; ++tj) {
        int n0 = bn + wn + tj*16 + q*4;
        int seg = n0 >> 8, c2 = n0 & 255;
        if (seg < 3) {
          bfx4 pk;
          #pragma unroll
          for (int r = 0; r < 4; ++r) pk[r] = f2bf(acc[ti][tj][r]);
          *(bfx4*)(qkv + (size_t)seg * NM + (size_t)m * 256 + c2) = pk;
        } else {
          float4 bg4 = *(const float4*)(bvec + c2);
          float4 o;
          o.x = 1.0f / (1.0f + __expf(-(acc[ti][tj][0] + bg4.x)));
          o.y = 1.0f / (1.0f + __expf(-(acc[ti][tj][1] + bg4.y)));
          o.z = 1.0f / (1.0f + __expf(-(acc[ti][tj][2] + bg4.z)));
          o.w = 1.0f / (1.0f + __expf(-(acc[ti][tj][3] + bg4.w)));
          // Gf fragment order: [d>>2][row][d&3], d = c2+r, row = m
          *(float4*)(gout + (size_t)(c2 >> 2) * 131072 + (size_t)m * 4) = o;
        }
      }
    }
  } else {
    #pragma unroll
    for (int ti = 0; ti < 4; ++ti) {
      int m = bm + wm + ti*16 + r16;
      #pragma unroll
      for (int tj = 0; tj < 4; ++tj) {
        int n0 = bn + wn + tj*16 + q*4;
        float4 bo4 = *(const float4*)(bvec + n0);
        float4 o;
        o.x = acc[ti][tj][0] + bo4.x;
        o.y = acc[ti][tj][1] + bo4.y;
        o.z = acc[ti][tj][2] + bo4.z;
        o.w = acc[ti][tj][3] + bo4.w;
        *(float4*)(gout + (size_t)m * 256 + n0) = o;
      }
    }
  }
}

// ---------------- MFMA flash attention: one block per (s,h) -----------------
// 4 waves x 64 i; 32-j chunks. S^T = K.Q^T; P -> per-wave LDS (bank-rotate
// swizzle); O^T = V^T.P^T. Bias via float4 frag loads; G via float4 frag loads.
__global__ __launch_bounds__(256, 4) void attn_k(
    const bfraw* __restrict__ Q, const bfraw* __restrict__ K,
    const bfraw* __restrict__ V, const float* __restrict__ Gf,
    const float* __restrict__ biasF, bfraw* __restrict__ gv)
{
  __shared__ bfraw Vt[32 * 256];       // [d][j], col j ^ ((d&7)<<3)  (16 KB)
  __shared__ bfraw Pb[4][64 * 32];     // per-wave [il][jl], rotate swiz (16 KB)

  const int s = blockIdx.x, h = blockIdx.y;
  const int t = threadIdx.x;
  const int w = t >> 6, lane = t & 63;
  const int r16 = lane & 15, q = lane >> 4;
  const size_t base = ((size_t)s * 256) * 256 + h * 32;   // + row*256 + d

  // stage V -> Vt (transposed, swizzled)
  #pragma unroll
  for (int e = 0; e < 4; ++e) {
    int idx = e * 256 + t;
    int j = idx >> 2, d8 = (idx & 3) << 3;
    bfx8 v = *(const bfx8*)(V + base + (size_t)j * 256 + d8);
    #pragma unroll
    for (int u = 0; u < 8; ++u) {
      int d = d8 + u;
      Vt[d * 256 + (j ^ ((d & 7) << 3))] = v[u];
    }
  }
  __syncthreads();

  const int ibase = w * 64;
  short8 qf[4];
  #pragma unroll
  for (int it = 0; it < 4; ++it)
    qf[it] = *(const short8*)(Q + base + (size_t)(ibase + it*16 + r16) * 256 + q*8);

  floatx4 accO[2][4];                  // [dt][it], O^T tiles
  #pragma unroll
  for (int dt = 0; dt < 2; ++dt)
    #pragma unroll
    for (int it = 0; it < 4; ++it)
      accO[dt][it] = (floatx4){0.f, 0.f, 0.f, 0.f};
  float lp[4] = {0.f, 0.f, 0.f, 0.f};

  bfraw* pb = &Pb[w][0];
  const float scale = 0.17677669529663687f;   // 1/sqrt(32)
  const float* bp = biasF + h * 65536;        // [j>>2][i][j&3]

  for (int jc = 0; jc < 8; ++jc) {
    const int j0 = jc * 32;
    short8 kf[2];
    #pragma unroll
    for (int jt = 0; jt < 2; ++jt)
      kf[jt] = *(const short8*)(K + base + (size_t)(j0 + jt*16 + r16) * 256 + q*8);

    floatx4 sc[2][4];                  // [jt][it]: row=j, col=i
    #pragma unroll
    for (int jt = 0; jt < 2; ++jt)
      #pragma unroll
      for (int it = 0; it < 4; ++it)
        sc[jt][it] = (floatx4){0.f, 0.f, 0.f, 0.f};
    #pragma unroll
    for (int jt = 0; jt < 2; ++jt)
      #pragma unroll
      for (int it = 0; it < 4; ++it)
        sc[jt][it] = __builtin_amdgcn_mfma_f32_16x16x32_bf16(
            kf[jt], qf[it], sc[jt][it], 0, 0, 0);

    // bias (float4 frag load) + exp + row-sum partials + pack P to LDS
    #pragma unroll
    for (int jt = 0; jt < 2; ++jt) {
      #pragma unroll
      for (int it = 0; it < 4; ++it) {
        int i  = ibase + it*16 + r16;
        int jb = j0 + jt*16 + q*4;
        int il = it*16 + r16;
        float4 b4 = *(const float4*)(bp + (jb >> 2) * 1024 + i * 4);
        float x0 = __expf(fmaf(sc[jt][it][0], scale, b4.x));
        float x1 = __expf(fmaf(sc[jt][it][1], scale, b4.y));
        float x2 = __expf(fmaf(sc[jt][it][2], scale, b4.z));
        float x3 = __expf(fmaf(sc[jt][it][3], scale, b4.w));
        lp[it] += (x0 + x1) + (x2 + x3);
        bfx4 p4;
        p4[0] = f2bf(x0); p4[1] = f2bf(x1); p4[2] = f2bf(x2); p4[3] = f2bf(x3);
        int colw = (jt*16 + q*4) ^ (((il >> 1) & 3) << 3);
        *(bfx4*)&pb[il * 32 + colw] = p4;
      }
    }

    // O^T += V^T(chunk) . P^T(chunk), K=32 -> 1 k-step
    short8 vf[2], pf[4];
    #pragma unroll
    for (int dt = 0; dt < 2; ++dt) {
      int d = dt*16 + r16;
      vf[dt] = *(const short8*)&Vt[d * 256 + ((j0 + q*8) ^ ((d & 7) << 3))];
    }
    #pragma unroll
    for (int it = 0; it < 4; ++it) {
      int il = it*16 + r16;
      pf[it] = *(const short8*)&pb[il * 32 + ((q*8) ^ (((il >> 1) & 3) << 3))];
    }
    #pragma unroll
    for (int dt = 0; dt < 2; ++dt)
      #pragma unroll
      for (int it = 0; it < 4; ++it)
        accO[dt][it] = __builtin_amdgcn_mfma_f32_16x16x32_bf16(
            vf[dt], pf[it], accO[dt][it], 0, 0, 0);
  }

  // full row sums: reduce across q-groups
  #pragma unroll
  for (int mk = 16; mk <= 32; mk <<= 1)
    #pragma unroll
    for (int it = 0; it < 4; ++it)
      lp[it] += __shfl_xor(lp[it], mk);

  // epilogue: lane col i = r16, rows d = dt*16 + q*4 + r
  #pragma unroll
  for (int it = 0; it < 4; ++it) {
    float invl = 1.0f / lp[it];
    int i = ibase + it*16 + r16;
    size_t row = (size_t)s * 256 + i;
    #pragma unroll
    for (int dt = 0; dt < 2; ++dt) {
      int d0 = h*32 + dt*16 + q*4;
      float4 g4 = *(const float4*)(Gf + (size_t)(d0 >> 2) * 131072 + row * 4);
      bfx4 h4, l4;
      float gg[4] = {g4.x, g4.y, g4.z, g4.w};
      #pragma unroll
      for (int r = 0; r < 4; ++r) {
        float o = gg[r] * accO[dt][it][r] * invl;
        bfraw hh = f2bf(o);
        h4[r] = hh;
        l4[r] = f2bf(o - bf2f(hh));
      }
      bfraw* gr = gv + row * 768 + d0;
      *(bfx4*)(gr)       = h4;
      *(bfx4*)(gr + 256) = l4;
      *(bfx4*)(gr + 512) = h4;
    }
  }
}

extern "C" void kernel_launch(void* const* d_in, const int* in_sizes, int n_in,
                              void* d_out, int out_size, void* d_ws, size_t ws_size,
                              hipStream_t stream) {
  const float* msa    = (const float*)d_in[0];
  const float* pair   = (const float*)d_in[1];
  const float* ln_m_g = (const float*)d_in[2];
  const float* ln_m_b = (const float*)d_in[3];
  const float* ln_p_g = (const float*)d_in[4];
  const float* ln_p_b = (const float*)d_in[5];
  const float* Wq     = (const float*)d_in[6];
  const float* Wk     = (const float*)d_in[7];
  const float* Wv     = (const float*)d_in[8];
  const float* Wp     = (const float*)d_in[9];
  const float* Wg     = (const float*)d_in[10];
  const float* bg     = (const float*)d_in[11];
  const float* Wo     = (const float*)d_in[12];
  const float* bo     = (const float*)d_in[13];
  float* out = (float*)d_out;

  char* wsb = (char*)d_ws;
  bfraw* Am      = (bfraw*)(wsb);                    // 48 MB  [32768][768]
  bfraw* QKV16   = (bfraw*)(wsb + 50331648);         // 48 MB  3 x [32768][256]
  float* Gfb     = (float*)(wsb + 100663296);        // 32 MB  [64][32768][4]
  float* biasF   = (float*)(wsb + 134217728);        //  2 MB  [8][64][256][4]
  bfraw* WqkvgT  = (bfraw*)(wsb + 136314880);        // 1.5 MB [1024][768]
  bfraw* WoT     = (bfraw*)(wsb + 137887744);        // .4 MB  [256][768]
  bfraw* gvp     = Am;                               // alias: Am dead after QKVG

  ln_msa_k<<<8192, 256, 0, stream>>>(msa, ln_m_g, ln_m_b, Am);
  wprep_qkvg_k<<<1024, 256, 0, stream>>>(Wq, Wk, Wv, Wg, WqkvgT);
  wprep_o_k<<<256, 256, 0, stream>>>(Wo, WoT);
  ln_pair_bias_k<<<16384, 256, 0, stream>>>(pair, ln_p_g, ln_p_b, Wp, biasF);

  mfma_gemm_k<<<dim3(256, 8), 256, 0, stream>>>(Am, WqkvgT, QKV16, Gfb, bg, 0);

  attn_k<<<dim3(128, 8), 256, 0, stream>>>(QKV16, QKV16 + NM, QKV16 + 2*NM,
                                           Gfb, biasF, gvp);

  mfma_gemm_k<<<dim3(256, 2), 256, 0, stream>>>(gvp, WoT, nullptr, out, bo, 1);
}

// Round 5
// 245.669 us; speedup vs baseline: 2.5536x; 1.2807x over previous
//
#include <hip/hip_runtime.h>

// MSARowAttentionWithPairBias — round 5: full fp16 pipeline.
// Round-2 insight: absmax is dominated by attention staging precision, not
// GEMM precision. fp16 (2^-11) staging beats bf16 (2^-9), so single-term
// fp16 GEMMs (K=256, 3x fewer FLOPs than split-bf16 K=768) suffice.
//  * A, W, Q, K, V, P, G, gv all fp16; accumulation fp32 (MFMA f16).
//  * GEMM: 128x128 tile, BK=32, global_load_lds w16, transposed product
//    epilogue (lane holds 4 consecutive n -> 8B packed stores).
//  * attn: round-4 structure (32-j chunks, frag-ordered bias float4 loads,
//    frag-ordered fp16 G, LDS 32KB, 4 blocks/CU).
// ws: Am 16M | QKV 48M | Gf 16M | biasF 2M | WqkvgT .5M | WoT .13M; gv=Am.

typedef _Float16 fp16;
typedef fp16 fp16x8 __attribute__((ext_vector_type(8)));
typedef fp16 fp16x4 __attribute__((ext_vector_type(4)));
typedef float floatx4 __attribute__((ext_vector_type(4)));

#define NM 8388608u            // 32768*256 elements

__device__ __forceinline__ void gld16(const fp16* g, fp16* l) {
  __builtin_amdgcn_global_load_lds(
      (const __attribute__((address_space(1))) unsigned int*)g,
      (__attribute__((address_space(3))) unsigned int*)l, 16, 0, 0);
}

// -------- LayerNorm msa rows (256 wide) -> A fp16 [row][256] ----------------
__global__ __launch_bounds__(256) void ln_msa_k(const float* __restrict__ x,
    const float* __restrict__ g, const float* __restrict__ b,
    fp16* __restrict__ Am)
{
  int row  = blockIdx.x * 4 + (threadIdx.x >> 6);
  int lane = threadIdx.x & 63;
  int base = row * 256 + lane * 4;
  float4 v = *(const float4*)(x + base);
  float s  = (v.x + v.y) + (v.z + v.w);
  float ss = (v.x*v.x + v.y*v.y) + (v.z*v.z + v.w*v.w);
  #pragma unroll
  for (int mk = 32; mk >= 1; mk >>= 1) {
    s  += __shfl_xor(s, mk);
    ss += __shfl_xor(ss, mk);
  }
  float mu  = s * (1.0f/256.0f);
  float var = ss * (1.0f/256.0f) - mu*mu;     // population var (jnp.var)
  float rs  = rsqrtf(var + 1e-5f);
  float4 gg = *(const float4*)(g + lane*4);
  float4 bb = *(const float4*)(b + lane*4);
  fp16x4 o;
  o[0] = (fp16)((v.x - mu) * rs * gg.x + bb.x);
  o[1] = (fp16)((v.y - mu) * rs * gg.y + bb.y);
  o[2] = (fp16)((v.z - mu) * rs * gg.z + bb.z);
  o[3] = (fp16)((v.w - mu) * rs * gg.w + bb.w);
  *(fp16x4*)(Am + (size_t)row * 256 + lane * 4) = o;
}

// -------- weight prep: W[k][n] fp32 -> WT[n][256] fp16 ----------------------
__global__ __launch_bounds__(256) void wprep_qkvg_k(const float* __restrict__ Wq,
    const float* __restrict__ Wk, const float* __restrict__ Wv,
    const float* __restrict__ Wg, fp16* __restrict__ WT)
{
  int n = blockIdx.x, k = threadIdx.x;
  const float* W = (n < 256) ? Wq : (n < 512) ? Wk : (n < 768) ? Wv : Wg;
  WT[(size_t)n * 256 + k] = (fp16)W[k * 256 + (n & 255)];
}

__global__ __launch_bounds__(256) void wprep_o_k(const float* __restrict__ Wo,
    fp16* __restrict__ WT)
{
  int n = blockIdx.x, k = threadIdx.x;
  WT[(size_t)n * 256 + k] = (fp16)Wo[k * 256 + n];
}

// --- pair LayerNorm (128 wide) + @Wp -> biasF[h][j>>2][i][j&3] (frag order) -
__global__ __launch_bounds__(256) void ln_pair_bias_k(const float* __restrict__ pair,
    const float* __restrict__ g, const float* __restrict__ b,
    const float* __restrict__ Wp, float* __restrict__ biasF)
{
  int row  = blockIdx.x * 4 + (threadIdx.x >> 6);   // i*256 + j
  int lane = threadIdx.x & 63;
  int base = row * 128 + lane * 2;
  float2 v = *(const float2*)(pair + base);
  float s  = v.x + v.y;
  float ss = v.x*v.x + v.y*v.y;
  #pragma unroll
  for (int mk = 32; mk >= 1; mk >>= 1) {
    s  += __shfl_xor(s, mk);
    ss += __shfl_xor(ss, mk);
  }
  float mu  = s * (1.0f/128.0f);
  float var = ss * (1.0f/128.0f) - mu*mu;
  float rs  = rsqrtf(var + 1e-5f);
  float2 gg = *(const float2*)(g + lane*2);
  float2 bb = *(const float2*)(b + lane*2);
  float p0 = (v.x - mu) * rs * gg.x + bb.x;
  float p1 = (v.y - mu) * rs * gg.y + bb.y;
  const float* w0 = Wp + (lane*2) * 8;
  float acc[8];
  #pragma unroll
  for (int hh = 0; hh < 8; ++hh)
    acc[hh] = p0 * w0[hh] + p1 * w0[8 + hh];
  #pragma unroll
  for (int mk = 32; mk >= 1; mk >>= 1)
    #pragma unroll
    for (int hh = 0; hh < 8; ++hh)
      acc[hh] += __shfl_xor(acc[hh], mk);
  int i = row >> 8, j = row & 255;
  #pragma unroll
  for (int hh = 0; hh < 8; ++hh)
    if (lane == hh)
      biasF[hh * 65536 + (j >> 2) * 1024 + i * 4 + (j & 3)] = acc[hh];
}

// -------- MFMA GEMM (transposed product): C = A[Mx256] @ WT[Nx256]^T --------
// acc[ti][tj] = mfma(bf[tj], af[ti]) -> lane: m = ..+r16, n = ..+q*4+r.
// mode 0: N=1024, segs 0..2 -> fp16 Q/K/V packed; seg 3 -> sigmoid -> Gf
//         fragment-ordered [d>>2][row][d&3] fp16.
// mode 1: N=256, fp32 out + bo, float4 stores.
__global__ __launch_bounds__(256, 2) void mfma_gemm_k(
    const fp16* __restrict__ A, const fp16* __restrict__ BT,
    fp16* __restrict__ qkv, fp16* __restrict__ gG, float* __restrict__ outF,
    const float* __restrict__ bvec, int mode)
{
  __shared__ fp16 As[128 * 32];
  __shared__ fp16 Bs[128 * 32];
  const int t  = threadIdx.x;
  const int bm = blockIdx.x * 128;
  const int bn = blockIdx.y * 128;
  const int lane = t & 63;
  const int w  = t >> 6;
  const int wm = (w & 1) * 64, wn = (w >> 1) * 64;
  const int r16 = lane & 15, q = lane >> 4;

  floatx4 acc[4][4];
  #pragma unroll
  for (int i = 0; i < 4; ++i)
    #pragma unroll
    for (int j = 0; j < 4; ++j)
      acc[i][j] = (floatx4){0.f, 0.f, 0.f, 0.f};

  for (int kb = 0; kb < 256; kb += 32) {
    #pragma unroll
    for (int i2 = 0; i2 < 2; ++i2) {
      int c = i2 * 256 + t;
      int rr = c >> 2, kq = (c & 3) << 3;
      gld16(A  + (size_t)(bm + rr) * 256 + kb + kq, As + c * 8);
      gld16(BT + (size_t)(bn + rr) * 256 + kb + kq, Bs + c * 8);
    }
    __syncthreads();
    fp16x8 af[4], bf[4];
    #pragma unroll
    for (int ti = 0; ti < 4; ++ti)
      af[ti] = *(const fp16x8*)&As[(wm + ti*16 + r16) * 32 + q * 8];
    #pragma unroll
    for (int tj = 0; tj < 4; ++tj)
      bf[tj] = *(const fp16x8*)&Bs[(wn + tj*16 + r16) * 32 + q * 8];
    #pragma unroll
    for (int ti = 0; ti < 4; ++ti)
      #pragma unroll
      for (int tj = 0; tj < 4; ++tj)
        acc[ti][tj] = __builtin_amdgcn_mfma_f32_16x16x32_f16(
            bf[tj], af[ti], acc[ti][tj], 0, 0, 0);   // transposed product
    __syncthreads();
  }

  if (mode == 0) {
    #pragma unroll
    for (int ti = 0; ti < 4; ++ti) {
      int m = bm + wm + ti*16 + r16;
      #pragma unroll
      for (int tj = 0; tj < 4; ++tj) {
        int n0 = bn + wn + tj*16 + q*4;
        int seg = n0 >> 8, c2 = n0 & 255;
        if (seg < 3) {
          fp16x4 pk;
          #pragma unroll
          for (int r = 0; r < 4; ++r) pk[r] = (fp16)acc[ti][tj][r];
          *(fp16x4*)(qkv + (size_t)seg * NM + (size_t)m * 256 + c2) = pk;
        } else {
          float4 bg4 = *(const float4*)(bvec + c2);
          fp16x4 o;
          o[0] = (fp16)(1.0f / (1.0f + __expf(-(acc[ti][tj][0] + bg4.x))));
          o[1] = (fp16)(1.0f / (1.0f + __expf(-(acc[ti][tj][1] + bg4.y))));
          o[2] = (fp16)(1.0f / (1.0f + __expf(-(acc[ti][tj][2] + bg4.z))));
          o[3] = (fp16)(1.0f / (1.0f + __expf(-(acc[ti][tj][3] + bg4.w))));
          // Gf fragment order: [d>>2][row][d&3], d = c2+r, row = m
          *(fp16x4*)(gG + (size_t)(c2 >> 2) * 131072 + (size_t)m * 4) = o;
        }
      }
    }
  } else {
    #pragma unroll
    for (int ti = 0; ti < 4; ++ti) {
      int m = bm + wm + ti*16 + r16;
      #pragma unroll
      for (int tj = 0; tj < 4; ++tj) {
        int n0 = bn + wn + tj*16 + q*4;
        float4 bo4 = *(const float4*)(bvec + n0);
        float4 o;
        o.x = acc[ti][tj][0] + bo4.x;
        o.y = acc[ti][tj][1] + bo4.y;
        o.z = acc[ti][tj][2] + bo4.z;
        o.w = acc[ti][tj][3] + bo4.w;
        *(float4*)(outF + (size_t)m * 256 + n0) = o;
      }
    }
  }
}

// ---------------- MFMA flash attention: one block per (s,h) -----------------
// 4 waves x 64 i; 32-j chunks. S^T = K.Q^T; P -> per-wave LDS (bank-rotate
// swizzle); O^T = V^T.P^T. Bias float4 frag loads; G fp16x4 frag loads.
__global__ __launch_bounds__(256, 4) void attn_k(
    const fp16* __restrict__ Q, const fp16* __restrict__ K,
    const fp16* __restrict__ V, const fp16* __restrict__ Gf,
    const float* __restrict__ biasF, fp16* __restrict__ gv)
{
  __shared__ fp16 Vt[32 * 256];       // [d][j], col j ^ ((d&7)<<3)  (16 KB)
  __shared__ fp16 Pb[4][64 * 32];     // per-wave [il][jl], rotate swiz (16 KB)

  const int s = blockIdx.x, h = blockIdx.y;
  const int t = threadIdx.x;
  const int w = t >> 6, lane = t & 63;
  const int r16 = lane & 15, q = lane >> 4;
  const size_t base = ((size_t)s * 256) * 256 + h * 32;   // + row*256 + d

  // stage V -> Vt (transposed, swizzled)
  #pragma unroll
  for (int e = 0; e < 4; ++e) {
    int idx = e * 256 + t;
    int j = idx >> 2, d8 = (idx & 3) << 3;
    fp16x8 v = *(const fp16x8*)(V + base + (size_t)j * 256 + d8);
    #pragma unroll
    for (int u = 0; u < 8; ++u) {
      int d = d8 + u;
      Vt[d * 256 + (j ^ ((d & 7) << 3))] = v[u];
    }
  }
  __syncthreads();

  const int ibase = w * 64;
  fp16x8 qf[4];
  #pragma unroll
  for (int it = 0; it < 4; ++it)
    qf[it] = *(const fp16x8*)(Q + base + (size_t)(ibase + it*16 + r16) * 256 + q*8);

  floatx4 accO[2][4];                  // [dt][it], O^T tiles
  #pragma unroll
  for (int dt = 0; dt < 2; ++dt)
    #pragma unroll
    for (int it = 0; it < 4; ++it)
      accO[dt][it] = (floatx4){0.f, 0.f, 0.f, 0.f};
  float lp[4] = {0.f, 0.f, 0.f, 0.f};

  fp16* pb = &Pb[w][0];
  const float scale = 0.17677669529663687f;   // 1/sqrt(32)
  const float* bp = biasF + h * 65536;        // [j>>2][i][j&3]

  for (int jc = 0; jc < 8; ++jc) {
    const int j0 = jc * 32;
    fp16x8 kf[2];
    #pragma unroll
    for (int jt = 0; jt < 2; ++jt)
      kf[jt] = *(const fp16x8*)(K + base + (size_t)(j0 + jt*16 + r16) * 256 + q*8);

    floatx4 sc[2][4];                  // [jt][it]: row=j, col=i
    #pragma unroll
    for (int jt = 0; jt < 2; ++jt)
      #pragma unroll
      for (int it = 0; it < 4; ++it)
        sc[jt][it] = (floatx4){0.f, 0.f, 0.f, 0.f};
    #pragma unroll
    for (int jt = 0; jt < 2; ++jt)
      #pragma unroll
      for (int it = 0; it < 4; ++it)
        sc[jt][it] = __builtin_amdgcn_mfma_f32_16x16x32_f16(
            kf[jt], qf[it], sc[jt][it], 0, 0, 0);

    // bias (float4 frag load) + exp + row-sum partials + pack P to LDS
    #pragma unroll
    for (int jt = 0; jt < 2; ++jt) {
      #pragma unroll
      for (int it = 0; it < 4; ++it) {
        int i  = ibase + it*16 + r16;
        int jb = j0 + jt*16 + q*4;
        int il = it*16 + r16;
        float4 b4 = *(const float4*)(bp + (jb >> 2) * 1024 + i * 4);
        float x0 = __expf(fmaf(sc[jt][it][0], scale, b4.x));
        float x1 = __expf(fmaf(sc[jt][it][1], scale, b4.y));
        float x2 = __expf(fmaf(sc[jt][it][2], scale, b4.z));
        float x3 = __expf(fmaf(sc[jt][it][3], scale, b4.w));
        lp[it] += (x0 + x1) + (x2 + x3);
        fp16x4 p4;
        p4[0] = (fp16)x0; p4[1] = (fp16)x1; p4[2] = (fp16)x2; p4[3] = (fp16)x3;
        int colw = (jt*16 + q*4) ^ (((il >> 1) & 3) << 3);
        *(fp16x4*)&pb[il * 32 + colw] = p4;
      }
    }

    // O^T += V^T(chunk) . P^T(chunk), K=32 -> 1 k-step
    fp16x8 vf[2], pf[4];
    #pragma unroll
    for (int dt = 0; dt < 2; ++dt) {
      int d = dt*16 + r16;
      vf[dt] = *(const fp16x8*)&Vt[d * 256 + ((j0 + q*8) ^ ((d & 7) << 3))];
    }
    #pragma unroll
    for (int it = 0; it < 4; ++it) {
      int il = it*16 + r16;
      pf[it] = *(const fp16x8*)&pb[il * 32 + ((q*8) ^ (((il >> 1) & 3) << 3))];
    }
    #pragma unroll
    for (int dt = 0; dt < 2; ++dt)
      #pragma unroll
      for (int it = 0; it < 4; ++it)
        accO[dt][it] = __builtin_amdgcn_mfma_f32_16x16x32_f16(
            vf[dt], pf[it], accO[dt][it], 0, 0, 0);
  }

  // full row sums: reduce across q-groups
  #pragma unroll
  for (int mk = 16; mk <= 32; mk <<= 1)
    #pragma unroll
    for (int it = 0; it < 4; ++it)
      lp[it] += __shfl_xor(lp[it], mk);

  // epilogue: lane col i = r16, rows d = dt*16 + q*4 + r
  #pragma unroll
  for (int it = 0; it < 4; ++it) {
    float invl = 1.0f / lp[it];
    int i = ibase + it*16 + r16;
    size_t row = (size_t)s * 256 + i;
    #pragma unroll
    for (int dt = 0; dt < 2; ++dt) {
      int d0 = h*32 + dt*16 + q*4;
      fp16x4 g4 = *(const fp16x4*)(Gf + (size_t)(d0 >> 2) * 131072 + row * 4);
      fp16x4 o4;
      #pragma unroll
      for (int r = 0; r < 4; ++r)
        o4[r] = (fp16)((float)g4[r] * accO[dt][it][r] * invl);
      *(fp16x4*)(gv + row * 256 + d0) = o4;
    }
  }
}

extern "C" void kernel_launch(void* const* d_in, const int* in_sizes, int n_in,
                              void* d_out, int out_size, void* d_ws, size_t ws_size,
                              hipStream_t stream) {
  const float* msa    = (const float*)d_in[0];
  const float* pair   = (const float*)d_in[1];
  const float* ln_m_g = (const float*)d_in[2];
  const float* ln_m_b = (const float*)d_in[3];
  const float* ln_p_g = (const float*)d_in[4];
  const float* ln_p_b = (const float*)d_in[5];
  const float* Wq     = (const float*)d_in[6];
  const float* Wk     = (const float*)d_in[7];
  const float* Wv     = (const float*)d_in[8];
  const float* Wp     = (const float*)d_in[9];
  const float* Wg     = (const float*)d_in[10];
  const float* bg     = (const float*)d_in[11];
  const float* Wo     = (const float*)d_in[12];
  const float* bo     = (const float*)d_in[13];
  float* out = (float*)d_out;

  char* wsb = (char*)d_ws;
  fp16*  Am      = (fp16*)(wsb);                     // 16 MB [32768][256]
  fp16*  QKV16   = (fp16*)(wsb + 16777216);          // 48 MB 3 x [32768][256]
  fp16*  Gfb     = (fp16*)(wsb + 67108864);          // 16 MB [64][32768][4]
  float* biasF   = (float*)(wsb + 83886080);         //  2 MB [8][64][256][4]
  fp16*  WqkvgT  = (fp16*)(wsb + 85983232);          // .5 MB [1024][256]
  fp16*  WoT     = (fp16*)(wsb + 86507520);          // .13MB [256][256]
  fp16*  gvp     = Am;                               // alias: Am dead after QKVG

  ln_msa_k<<<8192, 256, 0, stream>>>(msa, ln_m_g, ln_m_b, Am);
  wprep_qkvg_k<<<1024, 256, 0, stream>>>(Wq, Wk, Wv, Wg, WqkvgT);
  wprep_o_k<<<256, 256, 0, stream>>>(Wo, WoT);
  ln_pair_bias_k<<<16384, 256, 0, stream>>>(pair, ln_p_g, ln_p_b, Wp, biasF);

  mfma_gemm_k<<<dim3(256, 8), 256, 0, stream>>>(Am, WqkvgT, QKV16, Gfb,
                                                nullptr, bg, 0);

  attn_k<<<dim3(128, 8), 256, 0, stream>>>(QKV16, QKV16 + NM, QKV16 + 2*NM,
                                           Gfb, biasF, gvp);

  mfma_gemm_k<<<dim3(256, 2), 256, 0, stream>>>(gvp, WoT, nullptr, nullptr,
                                                out, bo, 1);
}

// Round 6
// 243.868 us; speedup vs baseline: 2.5725x; 1.0074x over previous
//
#include <hip/hip_runtime.h>

// MSARowAttentionWithPairBias — round 6: fix latency-bound ln_pair_bias.
// Round-5 counters: ln_pair_bias_k 47us, VALU 34%, hbm 5% -> latency-bound on
// 6-level x 8-acc shuffle chains (1 wave per 128-float row, 2 elems/lane).
// New structure: 8 lanes per row (wave = 8 rows): 16 contiguous floats/lane
// (4x float4 coalesced), 3-level LN reduce, 128 reg-FMA Wp projection
// (L1-resident 4KB table), 3-level x 8 reduce, lane sub writes head sub.
// Everything else identical to round 5 (full fp16 pipeline).

typedef _Float16 fp16;
typedef fp16 fp16x8 __attribute__((ext_vector_type(8)));
typedef fp16 fp16x4 __attribute__((ext_vector_type(4)));
typedef float floatx4 __attribute__((ext_vector_type(4)));

#define NM 8388608u            // 32768*256 elements

__device__ __forceinline__ void gld16(const fp16* g, fp16* l) {
  __builtin_amdgcn_global_load_lds(
      (const __attribute__((address_space(1))) unsigned int*)g,
      (__attribute__((address_space(3))) unsigned int*)l, 16, 0, 0);
}

// -------- LayerNorm msa rows (256 wide) -> A fp16 [row][256] ----------------
__global__ __launch_bounds__(256) void ln_msa_k(const float* __restrict__ x,
    const float* __restrict__ g, const float* __restrict__ b,
    fp16* __restrict__ Am)
{
  int row  = blockIdx.x * 4 + (threadIdx.x >> 6);
  int lane = threadIdx.x & 63;
  int base = row * 256 + lane * 4;
  float4 v = *(const float4*)(x + base);
  float s  = (v.x + v.y) + (v.z + v.w);
  float ss = (v.x*v.x + v.y*v.y) + (v.z*v.z + v.w*v.w);
  #pragma unroll
  for (int mk = 32; mk >= 1; mk >>= 1) {
    s  += __shfl_xor(s, mk);
    ss += __shfl_xor(ss, mk);
  }
  float mu  = s * (1.0f/256.0f);
  float var = ss * (1.0f/256.0f) - mu*mu;     // population var (jnp.var)
  float rs  = rsqrtf(var + 1e-5f);
  float4 gg = *(const float4*)(g + lane*4);
  float4 bb = *(const float4*)(b + lane*4);
  fp16x4 o;
  o[0] = (fp16)((v.x - mu) * rs * gg.x + bb.x);
  o[1] = (fp16)((v.y - mu) * rs * gg.y + bb.y);
  o[2] = (fp16)((v.z - mu) * rs * gg.z + bb.z);
  o[3] = (fp16)((v.w - mu) * rs * gg.w + bb.w);
  *(fp16x4*)(Am + (size_t)row * 256 + lane * 4) = o;
}

// -------- weight prep: W[k][n] fp32 -> WT[n][256] fp16 ----------------------
__global__ __launch_bounds__(256) void wprep_qkvg_k(const float* __restrict__ Wq,
    const float* __restrict__ Wk, const float* __restrict__ Wv,
    const float* __restrict__ Wg, fp16* __restrict__ WT)
{
  int n = blockIdx.x, k = threadIdx.x;
  const float* W = (n < 256) ? Wq : (n < 512) ? Wk : (n < 768) ? Wv : Wg;
  WT[(size_t)n * 256 + k] = (fp16)W[k * 256 + (n & 255)];
}

__global__ __launch_bounds__(256) void wprep_o_k(const float* __restrict__ Wo,
    fp16* __restrict__ WT)
{
  int n = blockIdx.x, k = threadIdx.x;
  WT[(size_t)n * 256 + k] = (fp16)Wo[k * 256 + n];
}

// --- pair LayerNorm + @Wp -> biasF[h][j>>2][i][j&3] (frag order) ------------
// 8 lanes per row; wave = 8 rows; block = 32 rows; grid = 2048.
__global__ __launch_bounds__(256) void ln_pair_bias_k(const float* __restrict__ pair,
    const float* __restrict__ g, const float* __restrict__ b,
    const float* __restrict__ Wp, float* __restrict__ biasF)
{
  const int t = threadIdx.x;
  const int w = t >> 6, lane = t & 63;
  const int grp = lane >> 3, sub = lane & 7;
  const int row = blockIdx.x * 32 + w * 8 + grp;   // i*256 + j
  const int c0  = sub * 16;

  const float* pr = pair + (size_t)row * 128 + c0;
  float4 v[4];
  #pragma unroll
  for (int e = 0; e < 4; ++e) v[e] = *(const float4*)(pr + e*4);

  float s = 0.f, ss = 0.f;
  #pragma unroll
  for (int e = 0; e < 4; ++e) {
    s  += (v[e].x + v[e].y) + (v[e].z + v[e].w);
    ss += (v[e].x*v[e].x + v[e].y*v[e].y) + (v[e].z*v[e].z + v[e].w*v[e].w);
  }
  #pragma unroll
  for (int mk = 1; mk <= 4; mk <<= 1) {
    s  += __shfl_xor(s, mk);
    ss += __shfl_xor(ss, mk);
  }
  float mu  = s * (1.0f/128.0f);
  float var = ss * (1.0f/128.0f) - mu*mu;
  float rs  = rsqrtf(var + 1e-5f);

  float acc[8] = {0.f,0.f,0.f,0.f,0.f,0.f,0.f,0.f};
  #pragma unroll
  for (int e = 0; e < 4; ++e) {
    float4 gg = *(const float4*)(g + c0 + e*4);
    float4 bb = *(const float4*)(b + c0 + e*4);
    float p[4];
    p[0] = (v[e].x - mu) * rs * gg.x + bb.x;
    p[1] = (v[e].y - mu) * rs * gg.y + bb.y;
    p[2] = (v[e].z - mu) * rs * gg.z + bb.z;
    p[3] = (v[e].w - mu) * rs * gg.w + bb.w;
    #pragma unroll
    for (int u = 0; u < 4; ++u) {
      const float* wr = Wp + (c0 + e*4 + u) * 8;
      float4 w0 = *(const float4*)(wr);
      float4 w1 = *(const float4*)(wr + 4);
      acc[0] = fmaf(p[u], w0.x, acc[0]);
      acc[1] = fmaf(p[u], w0.y, acc[1]);
      acc[2] = fmaf(p[u], w0.z, acc[2]);
      acc[3] = fmaf(p[u], w0.w, acc[3]);
      acc[4] = fmaf(p[u], w1.x, acc[4]);
      acc[5] = fmaf(p[u], w1.y, acc[5]);
      acc[6] = fmaf(p[u], w1.z, acc[6]);
      acc[7] = fmaf(p[u], w1.w, acc[7]);
    }
  }
  #pragma unroll
  for (int mk = 1; mk <= 4; mk <<= 1)
    #pragma unroll
    for (int hh = 0; hh < 8; ++hh)
      acc[hh] += __shfl_xor(acc[hh], mk);

  // lane sub owns head sub; frag-order store [h][j>>2][i][j&3]
  int i = row >> 8, j = row & 255;
  biasF[sub * 65536 + (j >> 2) * 1024 + i * 4 + (j & 3)] = acc[sub];
}

// -------- MFMA GEMM (transposed product): C = A[Mx256] @ WT[Nx256]^T --------
// acc[ti][tj] = mfma(bf[tj], af[ti]) -> lane: m = ..+r16, n = ..+q*4+r.
// mode 0: N=1024, segs 0..2 -> fp16 Q/K/V packed; seg 3 -> sigmoid -> Gf
//         fragment-ordered [d>>2][row][d&3] fp16.
// mode 1: N=256, fp32 out + bo, float4 stores.
__global__ __launch_bounds__(256, 2) void mfma_gemm_k(
    const fp16* __restrict__ A, const fp16* __restrict__ BT,
    fp16* __restrict__ qkv, fp16* __restrict__ gG, float* __restrict__ outF,
    const float* __restrict__ bvec, int mode)
{
  __shared__ fp16 As[128 * 32];
  __shared__ fp16 Bs[128 * 32];
  const int t  = threadIdx.x;
  const int bm = blockIdx.x * 128;
  const int bn = blockIdx.y * 128;
  const int lane = t & 63;
  const int w  = t >> 6;
  const int wm = (w & 1) * 64, wn = (w >> 1) * 64;
  const int r16 = lane & 15, q = lane >> 4;

  floatx4 acc[4][4];
  #pragma unroll
  for (int i = 0; i < 4; ++i)
    #pragma unroll
    for (int j = 0; j < 4; ++j)
      acc[i][j] = (floatx4){0.f, 0.f, 0.f, 0.f};

  for (int kb = 0; kb < 256; kb += 32) {
    #pragma unroll
    for (int i2 = 0; i2 < 2; ++i2) {
      int c = i2 * 256 + t;
      int rr = c >> 2, kq = (c & 3) << 3;
      gld16(A  + (size_t)(bm + rr) * 256 + kb + kq, As + c * 8);
      gld16(BT + (size_t)(bn + rr) * 256 + kb + kq, Bs + c * 8);
    }
    __syncthreads();
    fp16x8 af[4], bf[4];
    #pragma unroll
    for (int ti = 0; ti < 4; ++ti)
      af[ti] = *(const fp16x8*)&As[(wm + ti*16 + r16) * 32 + q * 8];
    #pragma unroll
    for (int tj = 0; tj < 4; ++tj)
      bf[tj] = *(const fp16x8*)&Bs[(wn + tj*16 + r16) * 32 + q * 8];
    #pragma unroll
    for (int ti = 0; ti < 4; ++ti)
      #pragma unroll
      for (int tj = 0; tj < 4; ++tj)
        acc[ti][tj] = __builtin_amdgcn_mfma_f32_16x16x32_f16(
            bf[tj], af[ti], acc[ti][tj], 0, 0, 0);   // transposed product
    __syncthreads();
  }

  if (mode == 0) {
    #pragma unroll
    for (int ti = 0; ti < 4; ++ti) {
      int m = bm + wm + ti*16 + r16;
      #pragma unroll
      for (int tj = 0; tj < 4; ++tj) {
        int n0 = bn + wn + tj*16 + q*4;
        int seg = n0 >> 8, c2 = n0 & 255;
        if (seg < 3) {
          fp16x4 pk;
          #pragma unroll
          for (int r = 0; r < 4; ++r) pk[r] = (fp16)acc[ti][tj][r];
          *(fp16x4*)(qkv + (size_t)seg * NM + (size_t)m * 256 + c2) = pk;
        } else {
          float4 bg4 = *(const float4*)(bvec + c2);
          fp16x4 o;
          o[0] = (fp16)(1.0f / (1.0f + __expf(-(acc[ti][tj][0] + bg4.x))));
          o[1] = (fp16)(1.0f / (1.0f + __expf(-(acc[ti][tj][1] + bg4.y))));
          o[2] = (fp16)(1.0f / (1.0f + __expf(-(acc[ti][tj][2] + bg4.z))));
          o[3] = (fp16)(1.0f / (1.0f + __expf(-(acc[ti][tj][3] + bg4.w))));
          // Gf fragment order: [d>>2][row][d&3], d = c2+r, row = m
          *(fp16x4*)(gG + (size_t)(c2 >> 2) * 131072 + (size_t)m * 4) = o;
        }
      }
    }
  } else {
    #pragma unroll
    for (int ti = 0; ti < 4; ++ti) {
      int m = bm + wm + ti*16 + r16;
      #pragma unroll
      for (int tj = 0; tj < 4; ++tj) {
        int n0 = bn + wn + tj*16 + q*4;
        float4 bo4 = *(const float4*)(bvec + n0);
        float4 o;
        o.x = acc[ti][tj][0] + bo4.x;
        o.y = acc[ti][tj][1] + bo4.y;
        o.z = acc[ti][tj][2] + bo4.z;
        o.w = acc[ti][tj][3] + bo4.w;
        *(float4*)(outF + (size_t)m * 256 + n0) = o;
      }
    }
  }
}

// ---------------- MFMA flash attention: one block per (s,h) -----------------
// 4 waves x 64 i; 32-j chunks. S^T = K.Q^T; P -> per-wave LDS (bank-rotate
// swizzle); O^T = V^T.P^T. Bias float4 frag loads; G fp16x4 frag loads.
__global__ __launch_bounds__(256, 4) void attn_k(
    const fp16* __restrict__ Q, const fp16* __restrict__ K,
    const fp16* __restrict__ V, const fp16* __restrict__ Gf,
    const float* __restrict__ biasF, fp16* __restrict__ gv)
{
  __shared__ fp16 Vt[32 * 256];       // [d][j], col j ^ ((d&7)<<3)  (16 KB)
  __shared__ fp16 Pb[4][64 * 32];     // per-wave [il][jl], rotate swiz (16 KB)

  const int s = blockIdx.x, h = blockIdx.y;
  const int t = threadIdx.x;
  const int w = t >> 6, lane = t & 63;
  const int r16 = lane & 15, q = lane >> 4;
  const size_t base = ((size_t)s * 256) * 256 + h * 32;   // + row*256 + d

  // stage V -> Vt (transposed, swizzled)
  #pragma unroll
  for (int e = 0; e < 4; ++e) {
    int idx = e * 256 + t;
    int j = idx >> 2, d8 = (idx & 3) << 3;
    fp16x8 v = *(const fp16x8*)(V + base + (size_t)j * 256 + d8);
    #pragma unroll
    for (int u = 0; u < 8; ++u) {
      int d = d8 + u;
      Vt[d * 256 + (j ^ ((d & 7) << 3))] = v[u];
    }
  }
  __syncthreads();

  const int ibase = w * 64;
  fp16x8 qf[4];
  #pragma unroll
  for (int it = 0; it < 4; ++it)
    qf[it] = *(const fp16x8*)(Q + base + (size_t)(ibase + it*16 + r16) * 256 + q*8);

  floatx4 accO[2][4];                  // [dt][it], O^T tiles
  #pragma unroll
  for (int dt = 0; dt < 2; ++dt)
    #pragma unroll
    for (int it = 0; it < 4; ++it)
      accO[dt][it] = (floatx4){0.f, 0.f, 0.f, 0.f};
  float lp[4] = {0.f, 0.f, 0.f, 0.f};

  fp16* pb = &Pb[w][0];
  const float scale = 0.17677669529663687f;   // 1/sqrt(32)
  const float* bp = biasF + h * 65536;        // [j>>2][i][j&3]

  for (int jc = 0; jc < 8; ++jc) {
    const int j0 = jc * 32;
    fp16x8 kf[2];
    #pragma unroll
    for (int jt = 0; jt < 2; ++jt)
      kf[jt] = *(const fp16x8*)(K + base + (size_t)(j0 + jt*16 + r16) * 256 + q*8);

    floatx4 sc[2][4];                  // [jt][it]: row=j, col=i
    #pragma unroll
    for (int jt = 0; jt < 2; ++jt)
      #pragma unroll
      for (int it = 0; it < 4; ++it)
        sc[jt][it] = (floatx4){0.f, 0.f, 0.f, 0.f};
    #pragma unroll
    for (int jt = 0; jt < 2; ++jt)
      #pragma unroll
      for (int it = 0; it < 4; ++it)
        sc[jt][it] = __builtin_amdgcn_mfma_f32_16x16x32_f16(
            kf[jt], qf[it], sc[jt][it], 0, 0, 0);

    // bias (float4 frag load) + exp + row-sum partials + pack P to LDS
    #pragma unroll
    for (int jt = 0; jt < 2; ++jt) {
      #pragma unroll
      for (int it = 0; it < 4; ++it) {
        int i  = ibase + it*16 + r16;
        int jb = j0 + jt*16 + q*4;
        int il = it*16 + r16;
        float4 b4 = *(const float4*)(bp + (jb >> 2) * 1024 + i * 4);
        float x0 = __expf(fmaf(sc[jt][it][0], scale, b4.x));
        float x1 = __expf(fmaf(sc[jt][it][1], scale, b4.y));
        float x2 = __expf(fmaf(sc[jt][it][2], scale, b4.z));
        float x3 = __expf(fmaf(sc[jt][it][3], scale, b4.w));
        lp[it] += (x0 + x1) + (x2 + x3);
        fp16x4 p4;
        p4[0] = (fp16)x0; p4[1] = (fp16)x1; p4[2] = (fp16)x2; p4[3] = (fp16)x3;
        int colw = (jt*16 + q*4) ^ (((il >> 1) & 3) << 3);
        *(fp16x4*)&pb[il * 32 + colw] = p4;
      }
    }

    // O^T += V^T(chunk) . P^T(chunk), K=32 -> 1 k-step
    fp16x8 vf[2], pf[4];
    #pragma unroll
    for (int dt = 0; dt < 2; ++dt) {
      int d = dt*16 + r16;
      vf[dt] = *(const fp16x8*)&Vt[d * 256 + ((j0 + q*8) ^ ((d & 7) << 3))];
    }
    #pragma unroll
    for (int it = 0; it < 4; ++it) {
      int il = it*16 + r16;
      pf[it] = *(const fp16x8*)&pb[il * 32 + ((q*8) ^ (((il >> 1) & 3) << 3))];
    }
    #pragma unroll
    for (int dt = 0; dt < 2; ++dt)
      #pragma unroll
      for (int it = 0; it < 4; ++it)
        accO[dt][it] = __builtin_amdgcn_mfma_f32_16x16x32_f16(
            vf[dt], pf[it], accO[dt][it], 0, 0, 0);
  }

  // full row sums: reduce across q-groups
  #pragma unroll
  for (int mk = 16; mk <= 32; mk <<= 1)
    #pragma unroll
    for (int it = 0; it < 4; ++it)
      lp[it] += __shfl_xor(lp[it], mk);

  // epilogue: lane col i = r16, rows d = dt*16 + q*4 + r
  #pragma unroll
  for (int it = 0; it < 4; ++it) {
    float invl = 1.0f / lp[it];
    int i = ibase + it*16 + r16;
    size_t row = (size_t)s * 256 + i;
    #pragma unroll
    for (int dt = 0; dt < 2; ++dt) {
      int d0 = h*32 + dt*16 + q*4;
      fp16x4 g4 = *(const fp16x4*)(Gf + (size_t)(d0 >> 2) * 131072 + row * 4);
      fp16x4 o4;
      #pragma unroll
      for (int r = 0; r < 4; ++r)
        o4[r] = (fp16)((float)g4[r] * accO[dt][it][r] * invl);
      *(fp16x4*)(gv + row * 256 + d0) = o4;
    }
  }
}

extern "C" void kernel_launch(void* const* d_in, const int* in_sizes, int n_in,
                              void* d_out, int out_size, void* d_ws, size_t ws_size,
                              hipStream_t stream) {
  const float* msa    = (const float*)d_in[0];
  const float* pair   = (const float*)d_in[1];
  const float* ln_m_g = (const float*)d_in[2];
  const float* ln_m_b = (const float*)d_in[3];
  const float* ln_p_g = (const float*)d_in[4];
  const float* ln_p_b = (const float*)d_in[5];
  const float* Wq     = (const float*)d_in[6];
  const float* Wk     = (const float*)d_in[7];
  const float* Wv     = (const float*)d_in[8];
  const float* Wp     = (const float*)d_in[9];
  const float* Wg     = (const float*)d_in[10];
  const float* bg     = (const float*)d_in[11];
  const float* Wo     = (const float*)d_in[12];
  const float* bo     = (const float*)d_in[13];
  float* out = (float*)d_out;

  char* wsb = (char*)d_ws;
  fp16*  Am      = (fp16*)(wsb);                     // 16 MB [32768][256]
  fp16*  QKV16   = (fp16*)(wsb + 16777216);          // 48 MB 3 x [32768][256]
  fp16*  Gfb     = (fp16*)(wsb + 67108864);          // 16 MB [64][32768][4]
  float* biasF   = (float*)(wsb + 83886080);         //  2 MB [8][64][256][4]
  fp16*  WqkvgT  = (fp16*)(wsb + 85983232);          // .5 MB [1024][256]
  fp16*  WoT     = (fp16*)(wsb + 86507520);          // .13MB [256][256]
  fp16*  gvp     = Am;                               // alias: Am dead after QKVG

  ln_msa_k<<<8192, 256, 0, stream>>>(msa, ln_m_g, ln_m_b, Am);
  wprep_qkvg_k<<<1024, 256, 0, stream>>>(Wq, Wk, Wv, Wg, WqkvgT);
  wprep_o_k<<<256, 256, 0, stream>>>(Wo, WoT);
  ln_pair_bias_k<<<2048, 256, 0, stream>>>(pair, ln_p_g, ln_p_b, Wp, biasF);

  mfma_gemm_k<<<dim3(256, 8), 256, 0, stream>>>(Am, WqkvgT, QKV16, Gfb,
                                                nullptr, bg, 0);

  attn_k<<<dim3(128, 8), 256, 0, stream>>>(QKV16, QKV16 + NM, QKV16 + 2*NM,
                                           Gfb, biasF, gvp);

  mfma_gemm_k<<<dim3(256, 2), 256, 0, stream>>>(gvp, WoT, nullptr, nullptr,
                                                out, bo, 1);
}